// Round 14
// baseline (238.010 us; speedup 1.0000x reference)
//
#include <hip/hip_runtime.h>
#include <hip/hip_fp16.h>

// ---------------- workspace layout (float offsets) ----------------
constexpr size_t OFF_Y0    = 0;         // 8*16*128*128 = 2097152
constexpr size_t OFF_Y1    = 2097152;   // 8*32*64*64   = 1048576
constexpr size_t OFF_Y2    = 3145728;   // 8*64*32*32   = 524288
constexpr size_t OFF_Y3    = 3670016;   // 8*128*16*16  = 262144 (ends 3932160)
constexpr size_t OFF_U     = 3670016;   // 8*15*1089 = 130680 (in dead Y3, after conv4 reads it)
constexpr size_t OFF_LUTC  = 0;         // compact fp16: 8*35937 uint2 = 574992 dwords (dead Y0)
constexpr size_t OFF_STATB = 4926640;
constexpr size_t OFF_STAT0 = OFF_STATB + 0;     // 8*16*2  = 256
constexpr size_t OFF_STAT1 = OFF_STATB + 256;   // 8*32*2  = 512
constexpr size_t OFF_STAT2 = OFF_STATB + 768;   // 8*64*2  = 1024
constexpr size_t OFF_STAT3 = OFF_STATB + 1792;  // 8*128*2 = 2048
constexpr size_t OFF_FEATS = OFF_STATB + 3840;  // 8*128   = 1024
constexpr size_t OFF_MAXB  = OFF_STATB + 4864;  // 8 per-batch absmax (uint-as-float)

__global__ __launch_bounds__(256) void zero_k(float* __restrict__ p, int n) {
  int i = blockIdx.x*256 + threadIdx.x;
  if (i < n) p[i] = 0.f;
}

// ---------------- unified tiled conv: stride-2 3x3 + lrelu (+stats / +mean) ----------------
template<int CIN, int COUT, int HIN, int WIN, int TH, int OCG, int PX, int OCT,
         int BLK, int MODE, int NPXPREV>
__global__ __launch_bounds__(BLK) void conv_tile(
    const float* __restrict__ xin, const float* __restrict__ wgt,
    const float* __restrict__ bias, const float* __restrict__ stat_in,
    const float* __restrict__ gam, const float* __restrict__ bet,
    float* __restrict__ yout, float* __restrict__ stat_out)
{
  constexpr int HOUT = HIN/2, WOUT = WIN/2;
  constexpr int SEG  = WOUT + 4;
  constexpr int XROW = 2*SEG;
  constexpr int XPI  = (2*TH+1)*XROW;
  constexpr int NT   = HOUT/TH;
  constexpr int NSTRIP_B = TH*WOUT/PX;
  constexpr int GPT  = OCG/OCT;
  static_assert(BLK == NSTRIP_B*GPT, "thread mapping mismatch");
  constexpr int R = NSTRIP_B < 64 ? NSTRIP_B : 64;

  __shared__ __align__(16) float xs[CIN*XPI];
  __shared__ float s_sc[CIN], s_sf[CIN];

  const int tid = threadIdx.x;
  const int lin = blockIdx.x;
  const int b = lin & 7;
  const int r2 = lin >> 3;
  const int tile = r2 % NT;
  const int ocb  = r2 / NT;

  if constexpr (MODE == 0) {
    if (tid == 0)      { s_sc[0] = 1.f/0.229f; s_sf[0] = -0.485f/0.229f; }
    else if (tid == 1) { s_sc[1] = 1.f/0.224f; s_sf[1] = -0.456f/0.224f; }
    else if (tid == 2) { s_sc[2] = 1.f/0.225f; s_sf[2] = -0.406f/0.225f; }
  } else {
    if (tid < CIN) {
      float S = stat_in[(b*CIN+tid)*2+0], Q = stat_in[(b*CIN+tid)*2+1];
      float mean = S*(1.0f/NPXPREV);
      float var  = Q*(1.0f/NPXPREV) - mean*mean;
      float rstd = rsqrtf(var + 1e-5f);
      float gg = gam[tid], bb = bet[tid];
      s_sc[tid] = gg*rstd;
      s_sf[tid] = bb - mean*gg*rstd;
    }
  }
  __syncthreads();

  const int iy0 = tile*(2*TH) - 1;
  const float* xb_g = xin + (size_t)b*CIN*HIN*WIN;
  for (int e = tid; e < CIN*(2*TH+1)*(WIN+2); e += BLK) {
    int ic  = e / ((2*TH+1)*(WIN+2));
    int rem = e - ic*((2*TH+1)*(WIN+2));
    int rr  = rem / (WIN+2);
    int cc  = rem - rr*(WIN+2);
    int iy = iy0 + rr, ix = cc - 1;
    float v = 0.f;
    if (iy >= 0 && iy < HIN && ix >= 0 && ix < WIN)
      v = s_sc[ic]*xb_g[(size_t)ic*HIN*WIN + iy*WIN + ix] + s_sf[ic];
    int off = (ix & 1) ? (SEG + ((ix+1) >> 1)) : (ix >> 1);
    xs[ic*XPI + rr*XROW + off] = v;
  }
  __syncthreads();

  const int s  = tid % NSTRIP_B;
  const int g  = tid / NSTRIP_B;
  const int r  = s / (WOUT/PX);
  const int c0 = (s % (WOUT/PX)) * PX;
  const int oc0 = ocb*OCG + g*OCT;

  float acc[OCT][PX];
  #pragma unroll
  for (int k = 0; k < OCT; ++k) {
    float bb = bias[oc0+k];
    #pragma unroll
    for (int j = 0; j < PX; ++j) acc[k][j] = bb;
  }

  float wv[OCT][9];
  #pragma unroll
  for (int k = 0; k < OCT; ++k) {
    const float* wp = wgt + ((size_t)(oc0+k)*CIN)*9;
    #pragma unroll
    for (int t = 0; t < 9; ++t) wv[k][t] = wp[t];
  }

  for (int ic = 0; ic < CIN; ++ic) {
    float wn[OCT][9];
    if (ic + 1 < CIN) {
      #pragma unroll
      for (int k = 0; k < OCT; ++k) {
        const float* wp = wgt + ((size_t)(oc0+k)*CIN + ic + 1)*9;
        #pragma unroll
        for (int t = 0; t < 9; ++t) wn[k][t] = wp[t];
      }
    }
    const float* xb = xs + ic*XPI;
    #pragma unroll
    for (int ky = 0; ky < 3; ++ky) {
      const float* rowp = xb + (2*r+ky)*XROW;
      float eb[PX], ob[PX+1];
      if constexpr (PX == 8) {
        *(float4*)&eb[0] = *(const float4*)(rowp + c0);
        *(float4*)&eb[4] = *(const float4*)(rowp + c0 + 4);
        *(float4*)&ob[0] = *(const float4*)(rowp + SEG + c0);
        *(float4*)&ob[4] = *(const float4*)(rowp + SEG + c0 + 4);
        ob[8] = rowp[SEG + c0 + 8];
      } else if constexpr (PX == 4) {
        *(float4*)&eb[0] = *(const float4*)(rowp + c0);
        *(float4*)&ob[0] = *(const float4*)(rowp + SEG + c0);
        ob[4] = rowp[SEG + c0 + 4];
      } else if constexpr (PX == 2) {
        *(float2*)&eb[0] = *(const float2*)(rowp + c0);
        *(float2*)&ob[0] = *(const float2*)(rowp + SEG + c0);
        ob[2] = rowp[SEG + c0 + 2];
      } else {
        eb[0] = rowp[c0];
        ob[0] = rowp[SEG + c0];
        ob[1] = rowp[SEG + c0 + 1];
      }
      #pragma unroll
      for (int k = 0; k < OCT; ++k) {
        float w0 = wv[k][ky*3], w1 = wv[k][ky*3+1], w2 = wv[k][ky*3+2];
        #pragma unroll
        for (int j = 0; j < PX; ++j)
          acc[k][j] += w0*ob[j] + w1*eb[j] + w2*ob[j+1];
      }
    }
    if (ic + 1 < CIN) {
      #pragma unroll
      for (int k = 0; k < OCT; ++k)
        #pragma unroll
        for (int t = 0; t < 9; ++t) wv[k][t] = wn[k][t];
    }
  }

  const int oy = tile*TH + r;
  if constexpr (MODE != 2) {
    float lsum[OCT], lsq[OCT];
    #pragma unroll
    for (int k = 0; k < OCT; ++k) {
      float ov[PX];
      float ls = 0.f, lq = 0.f;
      #pragma unroll
      for (int j = 0; j < PX; ++j) {
        float a = acc[k][j];
        a = a >= 0.f ? a : 0.2f*a;
        ov[j] = a; ls += a; lq += a*a;
      }
      lsum[k] = ls; lsq[k] = lq;
      float* yp = yout + (((size_t)b*COUT + oc0 + k)*HOUT + oy)*WOUT + c0;
      if constexpr (PX == 8) {
        *(float4*)yp = *(float4*)&ov[0];
        *(float4*)(yp+4) = *(float4*)&ov[4];
      } else if constexpr (PX == 4) {
        *(float4*)yp = *(float4*)&ov[0];
      } else if constexpr (PX == 2) {
        *(float2*)yp = *(float2*)&ov[0];
      } else {
        *yp = ov[0];
      }
    }
    #pragma unroll
    for (int k = 0; k < OCT; ++k) {
      #pragma unroll
      for (int off = R/2; off > 0; off >>= 1) {
        lsum[k] += __shfl_down(lsum[k], off);
        lsq[k]  += __shfl_down(lsq[k],  off);
      }
    }
    if ((tid & (R-1)) == 0) {
      #pragma unroll
      for (int k = 0; k < OCT; ++k) {
        atomicAdd(&stat_out[(b*COUT + oc0 + k)*2 + 0], lsum[k]);
        atomicAdd(&stat_out[(b*COUT + oc0 + k)*2 + 1], lsq[k]);
      }
    }
  } else {
    float a = acc[0][0];
    a = a >= 0.f ? a : 0.2f*a;
    #pragma unroll
    for (int off = R/2; off > 0; off >>= 1) a += __shfl_down(a, off);
    if ((tid & (R-1)) == 0) atomicAdd(&stat_out[b*COUT + oc0], a);
  }
}

// ---------------- U direct: head (redundant per block) + V fold + U slice ----------------
__global__ __launch_bounds__(256) void u_direct_kernel(
    const float* __restrict__ featsum, const float* __restrict__ w0, const float* __restrict__ b0,
    const float* __restrict__ w1, const float* __restrict__ b1,
    const float* __restrict__ luts, const float* __restrict__ wl, float* __restrict__ U)
{
  __shared__ float sh_h[128];
  __shared__ float sh_w[20];
  __shared__ float sh_v[20];
  const int tid = threadIdx.x;
  const int lin = blockIdx.x;            // bt + 8*(j*5+qb), 600 blocks
  const int bt = lin & 7;
  const int rest = lin >> 3;             // 0..74
  const int j = rest / 5, qb = rest % 5;
  const int s = j / 3, ch = j % 3;

  if (tid < 128) {
    const float* f = featsum + bt*128;
    const float* w = w0 + tid*128;
    float a = 0.f;
    for (int k = 0; k < 128; ++k) a += f[k]*w[k];
    a = b0[tid] + a*(1.0f/64.0f);
    float c = fminf(fmaxf(a + 3.f, 0.f), 6.f);
    sh_h[tid] = a * c * (1.f/6.f);
  }
  __syncthreads();
  if (tid < 20) {
    const float* w = w1 + tid*128;
    float a = b1[tid];
    for (int k = 0; k < 128; ++k) a += sh_h[k]*w[k];
    sh_w[tid] = a;
  }
  __syncthreads();
  if (tid < 20) {
    float a = 0.f;
    #pragma unroll
    for (int n = 0; n < 20; ++n)
      a += sh_w[n] * luts[(s*60 + n*3 + ch)*20 + tid];
    sh_v[tid] = a;
  }
  __syncthreads();
  const int q = qb*256 + tid;
  if (q < 1089) {
    float a = 0.f;
    #pragma unroll
    for (int w = 0; w < 20; ++w) a += sh_v[w] * wl[w*1089 + q];
    U[(size_t)(bt*15 + j)*1089 + q] = a;
  }
}

// ---------------- compact fp16 LUT + per-batch absmax ----------------
__global__ __launch_bounds__(256) void lutc_max_kernel(
    const float* __restrict__ U, const float* __restrict__ slay,
    uint2* __restrict__ lutc, unsigned* __restrict__ maxbuf)
{
  __shared__ float s_slay[165];
  __shared__ unsigned s_max;
  const int tid = threadIdx.x;
  if (tid < 165) s_slay[tid] = slay[tid];
  if (tid == 0) s_max = 0u;
  __syncthreads();
  const int lin = blockIdx.x;            // bt + 8*chunk, 141*8 blocks
  const int bt = lin & 7;
  const int i = (lin >> 3)*256 + tid;
  if (i < 35937) {
    int bi = i / 1089, rem = i - bi*1089, gi = rem / 33, ri = rem - gi*33;
    const float* Ub = U + (size_t)bt*15*1089;
    float v0 = 0.f, v1 = 0.f, v2 = 0.f;
    #pragma unroll
    for (int s = 0; s < 5; ++s) {
      v0 += s_slay[ri*5+s] * Ub[(s*3+0)*1089 + bi*33 + gi];
      v1 += s_slay[gi*5+s] * Ub[(s*3+1)*1089 + bi*33 + ri];
      v2 += s_slay[bi*5+s] * Ub[(s*3+2)*1089 + gi*33 + ri];
    }
    union { __half2 h2; unsigned u; } p0, p1;
    p0.h2 = __floats2half2_rn(v0, v1);
    p1.h2 = __floats2half2_rn(v2, 0.f);
    lutc[(size_t)bt*35937 + i] = make_uint2(p0.u, p1.u);
    float m = fmaxf(fmaxf(fabsf(v0), fabsf(v1)), fabsf(v2));
    atomicMax(&s_max, __float_as_uint(m));   // nonneg floats: uint cmp == float cmp
  }
  __syncthreads();
  if (tid == 0) atomicMax(&maxbuf[bt], s_max);
}

// ---------------- trilinear: stage + quantize-on-load into LDS, then gather ----------------
__device__ __forceinline__ void pair_acc(unsigned ca, unsigned cb, float wp, float fr,
                                         float& a0, float& a1, float& a2)
{
  float q0a = (float)(ca & 1023u), q1a = (float)((ca >> 10) & 1023u), q2a = (float)((ca >> 20) & 1023u);
  float q0b = (float)(cb & 1023u), q1b = (float)((cb >> 10) & 1023u), q2b = (float)((cb >> 20) & 1023u);
  a0 += wp * (q0a + fr*(q0b - q0a));
  a1 += wp * (q1a + fr*(q1b - q1a));
  a2 += wp * (q2a + fr*(q2b - q2a));
}

__global__ __launch_bounds__(1024) void trilin_lds_kernel(
    const float* __restrict__ img, const uint2* __restrict__ lutc,
    const unsigned* __restrict__ maxbuf, float* __restrict__ out)
{
  constexpr int NPX = 720*1280;
  constexpr int NV4 = NPX/4;            // 230400
  constexpr int PER_BLK = NV4/32;       // 7200 float4-groups per block
  __shared__ unsigned s_lut[35937];     // 143,748 B

  const int tid = threadIdx.x;
  const int lin = blockIdx.x;           // bt + 8*bb, 256 blocks
  const int bt = lin & 7;
  const int bb = lin >> 3;              // 0..31
  const float maxv  = __uint_as_float(maxbuf[bt]);
  const float enc   = maxv > 0.f ? 511.0f/maxv : 0.f;
  const float scale = maxv * (1.0f/511.0f);
  const float offc  = -512.0f * scale;

  const uint2* Lg = lutc + (size_t)bt*35937;
  for (int i = tid; i < 35937; i += 1024) {
    uint2 c = Lg[i];
    __half2 h01 = *(__half2*)&c.x;
    __half2 h2_ = *(__half2*)&c.y;
    float v0 = __low2float(h01), v1 = __high2float(h01), v2 = __low2float(h2_);
    int q0 = (int)rintf(v0*enc) + 512;
    int q1 = (int)rintf(v1*enc) + 512;
    int q2 = (int)rintf(v2*enc) + 512;
    q0 = q0 < 0 ? 0 : (q0 > 1023 ? 1023 : q0);
    q1 = q1 < 0 ? 0 : (q1 > 1023 ? 1023 : q1);
    q2 = q2 < 0 ? 0 : (q2 > 1023 ? 1023 : q2);
    s_lut[i] = (unsigned)q0 | ((unsigned)q1 << 10) | ((unsigned)q2 << 20);
  }
  __syncthreads();

  const float* ib = img + (size_t)bt*3*NPX;
  float* ob = out + (size_t)bt*3*NPX;
  const float invbin = 32.0f/1.000001f;
  const int vend = bb*PER_BLK + PER_BLK;

  for (int v = bb*PER_BLK + tid; v < vend; v += 1024) {
    float4 r4 = ((const float4*)ib)[v];
    float4 g4 = ((const float4*)(ib + NPX))[v];
    float4 b4 = ((const float4*)(ib + 2*NPX))[v];
    float4 ro, go, bo;
    float* rp = (float*)&ro; float* gp = (float*)&go; float* bp = (float*)&bo;
    #pragma unroll
    for (int j = 0; j < 4; ++j) {
      float r = ((float*)&r4)[j], g = ((float*)&g4)[j], b = ((float*)&b4)[j];
      float pr = r*invbin, pg = g*invbin, pb = b*invbin;
      int ri = (int)pr; ri = ri > 31 ? 31 : ri; ri = ri < 0 ? 0 : ri;
      int gi = (int)pg; gi = gi > 31 ? 31 : gi; gi = gi < 0 ? 0 : gi;
      int bi = (int)pb; bi = bi > 31 ? 31 : bi; bi = bi < 0 ? 0 : bi;
      float fr = pr - ri, fg = pg - gi, fb = pb - bi;
      int i00 = (bi*33 + gi)*33 + ri;
      unsigned c00a = s_lut[i00],        c00b = s_lut[i00 + 1];
      unsigned c01a = s_lut[i00 + 33],   c01b = s_lut[i00 + 34];
      unsigned c10a = s_lut[i00 + 1089], c10b = s_lut[i00 + 1090];
      unsigned c11a = s_lut[i00 + 1122], c11b = s_lut[i00 + 1123];
      float wb0 = 1.f - fb, wb1 = fb, wg0 = 1.f - fg, wg1 = fg;
      float a0 = 0.f, a1 = 0.f, a2 = 0.f;
      pair_acc(c00a, c00b, wb0*wg0, fr, a0, a1, a2);
      pair_acc(c01a, c01b, wb0*wg1, fr, a0, a1, a2);
      pair_acc(c10a, c10b, wb1*wg0, fr, a0, a1, a2);
      pair_acc(c11a, c11b, wb1*wg1, fr, a0, a1, a2);
      rp[j] = a0*scale + offc + r;
      gp[j] = a1*scale + offc + g;
      bp[j] = a2*scale + offc + b;
    }
    ((float4*)ob)[v]           = ro;
    ((float4*)(ob + NPX))[v]   = go;
    ((float4*)(ob + 2*NPX))[v] = bo;
  }
}

// ---------------- launcher ----------------
extern "C" void kernel_launch(void* const* d_in, const int* in_sizes, int n_in,
                              void* d_out, int out_size, void* d_ws, size_t ws_size,
                              hipStream_t stream) {
  const float* img     = (const float*)d_in[0];
  const float* img_org = (const float*)d_in[1];
  const float* c0w = (const float*)d_in[2];  const float* c0b = (const float*)d_in[3];
  const float* c1w = (const float*)d_in[4];  const float* c1b = (const float*)d_in[5];
  const float* c2w = (const float*)d_in[6];  const float* c2b = (const float*)d_in[7];
  const float* c3w = (const float*)d_in[8];  const float* c3b = (const float*)d_in[9];
  const float* c4w = (const float*)d_in[10]; const float* c4b = (const float*)d_in[11];
  const float* n0g = (const float*)d_in[12]; const float* n0b = (const float*)d_in[13];
  const float* n1g = (const float*)d_in[14]; const float* n1b = (const float*)d_in[15];
  const float* n2g = (const float*)d_in[16]; const float* n2b = (const float*)d_in[17];
  const float* n3g = (const float*)d_in[18]; const float* n3b = (const float*)d_in[19];
  const float* cls0_w = (const float*)d_in[20]; const float* cls0_b = (const float*)d_in[21];
  const float* cls1_w = (const float*)d_in[22]; const float* cls1_b = (const float*)d_in[23];
  const float* s_layers = (const float*)d_in[24];
  const float* w_layers = (const float*)d_in[25];
  const float* luts     = (const float*)d_in[26];
  float* ws = (float*)d_ws;
  float* out = (float*)d_out;

  // zero stats + featsum + maxbuf
  zero_k<<<20, 256, 0, stream>>>(ws + OFF_STATB, 4872);

  // conv0: 1 block/CU (best known for this layer)
  conv_tile<3,16,256,256, 4,16, 8,2, 512, 0, 1><<<256, 512, 0, stream>>>(
      img, c0w, c0b, nullptr, nullptr, nullptr, ws + OFF_Y0, ws + OFF_STAT0);
  // conv1-3: 2 blocks/CU (BLK=256, OCG=16, same tiles)
  conv_tile<16,32,128,128, 2,16, 4,2, 256, 1, 16384><<<512, 256, 0, stream>>>(
      ws + OFF_Y0, c1w, c1b, ws + OFF_STAT0, n0g, n0b, ws + OFF_Y1, ws + OFF_STAT1);
  conv_tile<32,64,64,64, 2,16, 2,2, 256, 1, 4096><<<512, 256, 0, stream>>>(
      ws + OFF_Y1, c2w, c2b, ws + OFF_STAT1, n1g, n1b, ws + OFF_Y2, ws + OFF_STAT2);
  conv_tile<64,128,32,32, 2,16, 1,2, 256, 1, 1024><<<512, 256, 0, stream>>>(
      ws + OFF_Y2, c3w, c3b, ws + OFF_STAT2, n2g, n2b, ws + OFF_Y3, ws + OFF_STAT3);
  conv_tile<128,128,16,16, 2,16, 1,1, 256, 2, 256><<<256, 256, 0, stream>>>(
      ws + OFF_Y3, c4w, c4b, ws + OFF_STAT3, n3g, n3b, nullptr, ws + OFF_FEATS);

  // U directly from luts/wl with in-block head
  u_direct_kernel<<<600, 256, 0, stream>>>(
      ws + OFF_FEATS, cls0_w, cls0_b, cls1_w, cls1_b,
      luts, w_layers, ws + OFF_U);

  // compact fp16 LUT + per-batch absmax
  lutc_max_kernel<<<141*8, 256, 0, stream>>>(
      ws + OFF_U, s_layers, (uint2*)(ws + OFF_LUTC), (unsigned*)(ws + OFF_MAXB));

  // trilinear: quantize-on-load into LDS, gather, residual
  trilin_lds_kernel<<<256, 1024, 0, stream>>>(
      img_org, (const uint2*)(ws + OFF_LUTC), (const unsigned*)(ws + OFF_MAXB), out);
}

// Round 15
// 193.503 us; speedup vs baseline: 1.2300x; 1.2300x over previous
//
#include <hip/hip_runtime.h>
#include <hip/hip_fp16.h>

typedef _Float16 h2 __attribute__((ext_vector_type(2)));

// ---------------- workspace layout (float offsets) ----------------
constexpr size_t OFF_Y0    = 0;         // 8*16*128*128 = 2097152
constexpr size_t OFF_Y1    = 2097152;   // 8*32*64*64   = 1048576
constexpr size_t OFF_Y2    = 3145728;   // 8*64*32*32   = 524288
constexpr size_t OFF_Y3    = 3670016;   // 8*128*16*16  = 262144 (ends 3932160)
constexpr size_t OFF_U     = 3670016;   // 8*15*1089 = 130680 (in dead Y3, after conv4 reads it)
constexpr size_t OFF_LUTC  = 0;         // compact fp16: 8*35937 uint2 = 574992 dwords (dead Y0)
constexpr size_t OFF_LUTQ  = 1048576;   // 10-bit codes: 8*35937 dwords = 287496
constexpr size_t OFF_STATB = 4926640;
constexpr size_t OFF_STAT0 = OFF_STATB + 0;     // 8*16*2  = 256
constexpr size_t OFF_STAT1 = OFF_STATB + 256;   // 8*32*2  = 512
constexpr size_t OFF_STAT2 = OFF_STATB + 768;   // 8*64*2  = 1024
constexpr size_t OFF_STAT3 = OFF_STATB + 1792;  // 8*128*2 = 2048
constexpr size_t OFF_FEATS = OFF_STATB + 3840;  // 8*128   = 1024
constexpr size_t OFF_MAXB  = OFF_STATB + 4864;  // 8 per-batch absmax (uint-as-float)

__global__ __launch_bounds__(256) void zero_k(float* __restrict__ p, int n) {
  int i = blockIdx.x*256 + threadIdx.x;
  if (i < n) p[i] = 0.f;
}

// ---------------- fp32 tiled conv (conv0 only: CIN=3, MEAN/STD fold) ----------------
template<int CIN, int COUT, int HIN, int WIN, int TH, int OCG, int PX, int OCT, int BLK>
__global__ __launch_bounds__(BLK) void conv_f32_first(
    const float* __restrict__ xin, const float* __restrict__ wgt,
    const float* __restrict__ bias,
    float* __restrict__ yout, float* __restrict__ stat_out)
{
  constexpr int HOUT = HIN/2, WOUT = WIN/2;
  constexpr int SEG  = WOUT + 4;
  constexpr int XROW = 2*SEG;
  constexpr int XPI  = (2*TH+1)*XROW;
  constexpr int NT   = HOUT/TH;
  constexpr int NSTRIP_B = TH*WOUT/PX;
  constexpr int GPT  = OCG/OCT;
  static_assert(BLK == NSTRIP_B*GPT, "thread mapping mismatch");
  constexpr int R = NSTRIP_B < 64 ? NSTRIP_B : 64;

  __shared__ __align__(16) float xs[CIN*XPI];
  __shared__ float s_sc[CIN], s_sf[CIN];

  const int tid = threadIdx.x;
  const int lin = blockIdx.x;
  const int b = lin & 7;
  const int r2 = lin >> 3;
  const int tile = r2 % NT;
  const int ocb  = r2 / NT;

  if (tid == 0)      { s_sc[0] = 1.f/0.229f; s_sf[0] = -0.485f/0.229f; }
  else if (tid == 1) { s_sc[1] = 1.f/0.224f; s_sf[1] = -0.456f/0.224f; }
  else if (tid == 2) { s_sc[2] = 1.f/0.225f; s_sf[2] = -0.406f/0.225f; }
  __syncthreads();

  const int iy0 = tile*(2*TH) - 1;
  const float* xb_g = xin + (size_t)b*CIN*HIN*WIN;
  for (int e = tid; e < CIN*(2*TH+1)*(WIN+2); e += BLK) {
    int ic  = e / ((2*TH+1)*(WIN+2));
    int rem = e - ic*((2*TH+1)*(WIN+2));
    int rr  = rem / (WIN+2);
    int cc  = rem - rr*(WIN+2);
    int iy = iy0 + rr, ix = cc - 1;
    float v = 0.f;
    if (iy >= 0 && iy < HIN && ix >= 0 && ix < WIN)
      v = s_sc[ic]*xb_g[(size_t)ic*HIN*WIN + iy*WIN + ix] + s_sf[ic];
    int off = (ix & 1) ? (SEG + ((ix+1) >> 1)) : (ix >> 1);
    xs[ic*XPI + rr*XROW + off] = v;
  }
  __syncthreads();

  const int s  = tid % NSTRIP_B;
  const int g  = tid / NSTRIP_B;
  const int r  = s / (WOUT/PX);
  const int c0 = (s % (WOUT/PX)) * PX;
  const int oc0 = ocb*OCG + g*OCT;

  float acc[OCT][PX];
  #pragma unroll
  for (int k = 0; k < OCT; ++k) {
    float bb = bias[oc0+k];
    #pragma unroll
    for (int j = 0; j < PX; ++j) acc[k][j] = bb;
  }

  for (int ic = 0; ic < CIN; ++ic) {
    float wv[OCT][9];
    #pragma unroll
    for (int k = 0; k < OCT; ++k) {
      const float* wp = wgt + ((size_t)(oc0+k)*CIN + ic)*9;
      #pragma unroll
      for (int t = 0; t < 9; ++t) wv[k][t] = wp[t];
    }
    const float* xb = xs + ic*XPI;
    #pragma unroll
    for (int ky = 0; ky < 3; ++ky) {
      const float* rowp = xb + (2*r+ky)*XROW;
      float eb[PX], ob[PX+1];
      static_assert(PX == 8, "conv0 uses PX=8");
      *(float4*)&eb[0] = *(const float4*)(rowp + c0);
      *(float4*)&eb[4] = *(const float4*)(rowp + c0 + 4);
      *(float4*)&ob[0] = *(const float4*)(rowp + SEG + c0);
      *(float4*)&ob[4] = *(const float4*)(rowp + SEG + c0 + 4);
      ob[8] = rowp[SEG + c0 + 8];
      #pragma unroll
      for (int k = 0; k < OCT; ++k) {
        float w0 = wv[k][ky*3], w1 = wv[k][ky*3+1], w2 = wv[k][ky*3+2];
        #pragma unroll
        for (int j = 0; j < PX; ++j)
          acc[k][j] += w0*ob[j] + w1*eb[j] + w2*ob[j+1];
      }
    }
  }

  const int oy = tile*TH + r;
  float lsum[OCT], lsq[OCT];
  #pragma unroll
  for (int k = 0; k < OCT; ++k) {
    float ov[PX];
    float ls = 0.f, lq = 0.f;
    #pragma unroll
    for (int j = 0; j < PX; ++j) {
      float a = acc[k][j];
      a = a >= 0.f ? a : 0.2f*a;
      ov[j] = a; ls += a; lq += a*a;
    }
    lsum[k] = ls; lsq[k] = lq;
    float* yp = yout + (((size_t)b*COUT + oc0 + k)*HOUT + oy)*WOUT + c0;
    *(float4*)yp = *(float4*)&ov[0];
    *(float4*)(yp+4) = *(float4*)&ov[4];
  }
  #pragma unroll
  for (int k = 0; k < OCT; ++k) {
    #pragma unroll
    for (int off = R/2; off > 0; off >>= 1) {
      lsum[k] += __shfl_down(lsum[k], off);
      lsq[k]  += __shfl_down(lsq[k],  off);
    }
  }
  if ((tid & (R-1)) == 0) {
    #pragma unroll
    for (int k = 0; k < OCT; ++k) {
      atomicAdd(&stat_out[(b*COUT + oc0 + k)*2 + 0], lsum[k]);
      atomicAdd(&stat_out[(b*COUT + oc0 + k)*2 + 1], lsq[k]);
    }
  }
}

// ---------------- fp16 channel-pair conv (conv1-4): stride-2 3x3 + lrelu via v_dot2 --------
// MODE: 1 = mid (inorm from raw stats, write y + stats), 2 = last (mean -> featsum)
template<int CIN, int COUT, int HIN, int WIN, int TH, int OCG, int PX, int OCT,
         int BLK, int MODE, int NPXPREV>
__global__ __launch_bounds__(BLK) void conv_h2(
    const float* __restrict__ xin, const float* __restrict__ wgt,
    const float* __restrict__ bias, const float* __restrict__ stat_in,
    const float* __restrict__ gam, const float* __restrict__ bet,
    float* __restrict__ yout, float* __restrict__ stat_out)
{
  constexpr int CINH = CIN/2;
  constexpr int HOUT = HIN/2, WOUT = WIN/2;
  constexpr int SEG  = WOUT + 4;          // mult of 4
  constexpr int XROW = 2*SEG;
  constexpr int XPI  = (2*TH+1)*XROW;
  constexpr int NT   = HOUT/TH;
  constexpr int NSTRIP_B = TH*WOUT/PX;
  constexpr int GPT  = OCG/OCT;
  static_assert(BLK == NSTRIP_B*GPT, "thread mapping mismatch");
  constexpr int R = NSTRIP_B < 64 ? NSTRIP_B : 64;

  __shared__ __align__(16) h2 xs[CINH*XPI];
  __shared__ float s_sc[CIN], s_sf[CIN];

  const int tid = threadIdx.x;
  const int lin = blockIdx.x;
  const int b = lin & 7;
  const int r2 = lin >> 3;
  const int tile = r2 % NT;
  const int ocb  = r2 / NT;

  if (tid < CIN) {
    float S = stat_in[(b*CIN+tid)*2+0], Q = stat_in[(b*CIN+tid)*2+1];
    float mean = S*(1.0f/NPXPREV);
    float var  = Q*(1.0f/NPXPREV) - mean*mean;
    float rstd = rsqrtf(var + 1e-5f);
    float gg = gam[tid], bb = bet[tid];
    s_sc[tid] = gg*rstd;
    s_sf[tid] = bb - mean*gg*rstd;
  }
  __syncthreads();

  const int iy0 = tile*(2*TH) - 1;
  const float* xb_g = xin + (size_t)b*CIN*HIN*WIN;
  for (int e = tid; e < CINH*(2*TH+1)*(WIN+2); e += BLK) {
    int icp = e / ((2*TH+1)*(WIN+2));
    int rem = e - icp*((2*TH+1)*(WIN+2));
    int rr  = rem / (WIN+2);
    int cc  = rem - rr*(WIN+2);
    int iy = iy0 + rr, ix = cc - 1;
    float v0 = 0.f, v1 = 0.f;
    if (iy >= 0 && iy < HIN && ix >= 0 && ix < WIN) {
      int ic0 = 2*icp;
      v0 = s_sc[ic0]  *xb_g[(size_t)ic0*HIN*WIN + iy*WIN + ix]     + s_sf[ic0];
      v1 = s_sc[ic0+1]*xb_g[(size_t)(ic0+1)*HIN*WIN + iy*WIN + ix] + s_sf[ic0+1];
    }
    int off = (ix & 1) ? (SEG + ((ix+1) >> 1)) : (ix >> 1);
    h2 p; p[0] = (_Float16)v0; p[1] = (_Float16)v1;
    xs[icp*XPI + rr*XROW + off] = p;
  }
  __syncthreads();

  const int s  = tid % NSTRIP_B;
  const int g  = tid / NSTRIP_B;
  const int r  = s / (WOUT/PX);
  const int c0 = (s % (WOUT/PX)) * PX;
  const int oc0 = ocb*OCG + g*OCT;

  float acc[OCT][PX];
  #pragma unroll
  for (int k = 0; k < OCT; ++k) {
    float bb = bias[oc0+k];
    #pragma unroll
    for (int j = 0; j < PX; ++j) acc[k][j] = bb;
  }

  for (int icp = 0; icp < CINH; ++icp) {
    h2 wv[OCT][9];
    #pragma unroll
    for (int k = 0; k < OCT; ++k) {
      const float* wp0 = wgt + ((size_t)(oc0+k)*CIN + 2*icp)*9;
      const float* wp1 = wp0 + 9;
      #pragma unroll
      for (int t = 0; t < 9; ++t) {
        h2 w; w[0] = (_Float16)wp0[t]; w[1] = (_Float16)wp1[t];
        wv[k][t] = w;
      }
    }
    const h2* xb = xs + icp*XPI;
    #pragma unroll
    for (int ky = 0; ky < 3; ++ky) {
      const h2* rowp = xb + (2*r+ky)*XROW;
      h2 eb[PX], ob[PX+1];
      if constexpr (PX == 4) {
        *(uint4*)&eb[0] = *(const uint4*)(rowp + c0);
        *(uint4*)&ob[0] = *(const uint4*)(rowp + SEG + c0);
        ob[4] = rowp[SEG + c0 + 4];
      } else if constexpr (PX == 2) {
        *(uint2*)&eb[0] = *(const uint2*)(rowp + c0);
        *(uint2*)&ob[0] = *(const uint2*)(rowp + SEG + c0);
        ob[2] = rowp[SEG + c0 + 2];
      } else {
        eb[0] = rowp[c0];
        ob[0] = rowp[SEG + c0];
        ob[1] = rowp[SEG + c0 + 1];
      }
      #pragma unroll
      for (int k = 0; k < OCT; ++k) {
        h2 w0 = wv[k][ky*3], w1 = wv[k][ky*3+1], w2 = wv[k][ky*3+2];
        #pragma unroll
        for (int j = 0; j < PX; ++j) {
          float a = acc[k][j];
          a = __builtin_amdgcn_fdot2(w0, ob[j],   a, false);
          a = __builtin_amdgcn_fdot2(w1, eb[j],   a, false);
          a = __builtin_amdgcn_fdot2(w2, ob[j+1], a, false);
          acc[k][j] = a;
        }
      }
    }
  }

  const int oy = tile*TH + r;
  if constexpr (MODE != 2) {
    float lsum[OCT], lsq[OCT];
    #pragma unroll
    for (int k = 0; k < OCT; ++k) {
      float ov[PX];
      float ls = 0.f, lq = 0.f;
      #pragma unroll
      for (int j = 0; j < PX; ++j) {
        float a = acc[k][j];
        a = a >= 0.f ? a : 0.2f*a;
        ov[j] = a; ls += a; lq += a*a;
      }
      lsum[k] = ls; lsq[k] = lq;
      float* yp = yout + (((size_t)b*COUT + oc0 + k)*HOUT + oy)*WOUT + c0;
      if constexpr (PX == 4) {
        *(float4*)yp = *(float4*)&ov[0];
      } else if constexpr (PX == 2) {
        *(float2*)yp = *(float2*)&ov[0];
      } else {
        *yp = ov[0];
      }
    }
    #pragma unroll
    for (int k = 0; k < OCT; ++k) {
      #pragma unroll
      for (int off = R/2; off > 0; off >>= 1) {
        lsum[k] += __shfl_down(lsum[k], off);
        lsq[k]  += __shfl_down(lsq[k],  off);
      }
    }
    if ((tid & (R-1)) == 0) {
      #pragma unroll
      for (int k = 0; k < OCT; ++k) {
        atomicAdd(&stat_out[(b*COUT + oc0 + k)*2 + 0], lsum[k]);
        atomicAdd(&stat_out[(b*COUT + oc0 + k)*2 + 1], lsq[k]);
      }
    }
  } else {
    float a = acc[0][0];
    a = a >= 0.f ? a : 0.2f*a;
    #pragma unroll
    for (int off = R/2; off > 0; off >>= 1) a += __shfl_down(a, off);
    if ((tid & (R-1)) == 0) atomicAdd(&stat_out[b*COUT + oc0], a);
  }
}

// ---------------- U direct: head (redundant per block) + V fold + U slice ----------------
__global__ __launch_bounds__(256) void u_direct_kernel(
    const float* __restrict__ featsum, const float* __restrict__ w0, const float* __restrict__ b0,
    const float* __restrict__ w1, const float* __restrict__ b1,
    const float* __restrict__ luts, const float* __restrict__ wl, float* __restrict__ U)
{
  __shared__ float sh_h[128];
  __shared__ float sh_w[20];
  __shared__ float sh_v[20];
  const int tid = threadIdx.x;
  const int lin = blockIdx.x;            // bt + 8*(j*5+qb), 600 blocks
  const int bt = lin & 7;
  const int rest = lin >> 3;             // 0..74
  const int j = rest / 5, qb = rest % 5;
  const int s = j / 3, ch = j % 3;

  if (tid < 128) {
    const float* f = featsum + bt*128;
    const float* w = w0 + tid*128;
    float a = 0.f;
    for (int k = 0; k < 128; ++k) a += f[k]*w[k];
    a = b0[tid] + a*(1.0f/64.0f);
    float c = fminf(fmaxf(a + 3.f, 0.f), 6.f);
    sh_h[tid] = a * c * (1.f/6.f);
  }
  __syncthreads();
  if (tid < 20) {
    const float* w = w1 + tid*128;
    float a = b1[tid];
    for (int k = 0; k < 128; ++k) a += sh_h[k]*w[k];
    sh_w[tid] = a;
  }
  __syncthreads();
  if (tid < 20) {
    float a = 0.f;
    #pragma unroll
    for (int n = 0; n < 20; ++n)
      a += sh_w[n] * luts[(s*60 + n*3 + ch)*20 + tid];
    sh_v[tid] = a;
  }
  __syncthreads();
  const int q = qb*256 + tid;
  if (q < 1089) {
    float a = 0.f;
    #pragma unroll
    for (int w = 0; w < 20; ++w) a += sh_v[w] * wl[w*1089 + q];
    U[(size_t)(bt*15 + j)*1089 + q] = a;
  }
}

// ---------------- compact fp16 LUT + per-batch absmax ----------------
__global__ __launch_bounds__(256) void lutc_max_kernel(
    const float* __restrict__ U, const float* __restrict__ slay,
    uint2* __restrict__ lutc, unsigned* __restrict__ maxbuf)
{
  __shared__ float s_slay[165];
  __shared__ unsigned s_max;
  const int tid = threadIdx.x;
  if (tid < 165) s_slay[tid] = slay[tid];
  if (tid == 0) s_max = 0u;
  __syncthreads();
  const int lin = blockIdx.x;            // bt + 8*chunk, 141*8 blocks
  const int bt = lin & 7;
  const int i = (lin >> 3)*256 + tid;
  if (i < 35937) {
    int bi = i / 1089, rem = i - bi*1089, gi = rem / 33, ri = rem - gi*33;
    const float* Ub = U + (size_t)bt*15*1089;
    float v0 = 0.f, v1 = 0.f, v2 = 0.f;
    #pragma unroll
    for (int s = 0; s < 5; ++s) {
      v0 += s_slay[ri*5+s] * Ub[(s*3+0)*1089 + bi*33 + gi];
      v1 += s_slay[gi*5+s] * Ub[(s*3+1)*1089 + bi*33 + ri];
      v2 += s_slay[bi*5+s] * Ub[(s*3+2)*1089 + gi*33 + ri];
    }
    union { __half2 h2v; unsigned u; } p0, p1;
    p0.h2v = __floats2half2_rn(v0, v1);
    p1.h2v = __floats2half2_rn(v2, 0.f);
    lutc[(size_t)bt*35937 + i] = make_uint2(p0.u, p1.u);
    float m = fmaxf(fmaxf(fabsf(v0), fabsf(v1)), fabsf(v2));
    atomicMax(&s_max, __float_as_uint(m));   // nonneg floats: uint cmp == float cmp
  }
  __syncthreads();
  if (tid == 0) atomicMax(&maxbuf[bt], s_max);
}

// ---------------- quantize compact fp16 -> 3x10-bit codes (4B/corner) ----------------
__global__ __launch_bounds__(256) void lutq_kernel(
    const uint2* __restrict__ lutc, const unsigned* __restrict__ maxbuf,
    unsigned* __restrict__ lutq)
{
  const int lin = blockIdx.x;            // bt + 8*chunk, 141*8 blocks
  const int bt = lin & 7;
  const int i = (lin >> 3)*256 + threadIdx.x;
  if (i >= 35937) return;
  float maxv = __uint_as_float(maxbuf[bt]);
  float enc = maxv > 0.f ? 511.0f/maxv : 0.f;
  uint2 c = lutc[(size_t)bt*35937 + i];
  __half2 h01 = *(__half2*)&c.x;
  __half2 h2_ = *(__half2*)&c.y;
  float v0 = __low2float(h01), v1 = __high2float(h01), v2 = __low2float(h2_);
  int q0 = (int)rintf(v0*enc) + 512;
  int q1 = (int)rintf(v1*enc) + 512;
  int q2 = (int)rintf(v2*enc) + 512;
  q0 = q0 < 0 ? 0 : (q0 > 1023 ? 1023 : q0);
  q1 = q1 < 0 ? 0 : (q1 > 1023 ? 1023 : q1);
  q2 = q2 < 0 ? 0 : (q2 > 1023 ? 1023 : q2);
  lutq[(size_t)bt*35937 + i] = (unsigned)q0 | ((unsigned)q1 << 10) | ((unsigned)q2 << 20);
}

// ---------------- trilinear from LDS-resident quantized LUT + residual ----------------
__device__ __forceinline__ void pair_acc(unsigned ca, unsigned cb, float wp, float fr,
                                         float& a0, float& a1, float& a2)
{
  float q0a = (float)(ca & 1023u), q1a = (float)((ca >> 10) & 1023u), q2a = (float)((ca >> 20) & 1023u);
  float q0b = (float)(cb & 1023u), q1b = (float)((cb >> 10) & 1023u), q2b = (float)((cb >> 20) & 1023u);
  a0 += wp * (q0a + fr*(q0b - q0a));
  a1 += wp * (q1a + fr*(q1b - q1a));
  a2 += wp * (q2a + fr*(q2b - q2a));
}

__global__ __launch_bounds__(1024) void trilin_lds_kernel(
    const float* __restrict__ img, const unsigned* __restrict__ lutq,
    const unsigned* __restrict__ maxbuf, float* __restrict__ out)
{
  constexpr int NPX = 720*1280;
  constexpr int NV4 = NPX/4;            // 230400
  constexpr int PER_BLK = NV4/32;       // 7200 float4-groups per block
  __shared__ unsigned s_lut[35937];     // 143,748 B

  const int tid = threadIdx.x;
  const int lin = blockIdx.x;           // bt + 8*bb, 256 blocks
  const int bt = lin & 7;
  const int bb = lin >> 3;              // 0..31
  const unsigned* Lg = lutq + (size_t)bt*35937;
  for (int i = tid; i < 35937; i += 1024) s_lut[i] = Lg[i];
  __syncthreads();

  const float maxv  = __uint_as_float(maxbuf[bt]);
  const float scale = maxv * (1.0f/511.0f);
  const float offc  = -512.0f * scale;
  const float* ib = img + (size_t)bt*3*NPX;
  float* ob = out + (size_t)bt*3*NPX;
  const float invbin = 32.0f/1.000001f;
  const int vend = bb*PER_BLK + PER_BLK;

  for (int v = bb*PER_BLK + tid; v < vend; v += 1024) {
    float4 r4 = ((const float4*)ib)[v];
    float4 g4 = ((const float4*)(ib + NPX))[v];
    float4 b4 = ((const float4*)(ib + 2*NPX))[v];
    float4 ro, go, bo;
    float* rp = (float*)&ro; float* gp = (float*)&go; float* bp = (float*)&bo;
    #pragma unroll
    for (int j = 0; j < 4; ++j) {
      float r = ((float*)&r4)[j], g = ((float*)&g4)[j], b = ((float*)&b4)[j];
      float pr = r*invbin, pg = g*invbin, pb = b*invbin;
      int ri = (int)pr; ri = ri > 31 ? 31 : ri; ri = ri < 0 ? 0 : ri;
      int gi = (int)pg; gi = gi > 31 ? 31 : gi; gi = gi < 0 ? 0 : gi;
      int bi = (int)pb; bi = bi > 31 ? 31 : bi; bi = bi < 0 ? 0 : bi;
      float fr = pr - ri, fg = pg - gi, fb = pb - bi;
      int i00 = (bi*33 + gi)*33 + ri;
      unsigned c00a = s_lut[i00],        c00b = s_lut[i00 + 1];
      unsigned c01a = s_lut[i00 + 33],   c01b = s_lut[i00 + 34];
      unsigned c10a = s_lut[i00 + 1089], c10b = s_lut[i00 + 1090];
      unsigned c11a = s_lut[i00 + 1122], c11b = s_lut[i00 + 1123];
      float wb0 = 1.f - fb, wb1 = fb, wg0 = 1.f - fg, wg1 = fg;
      float a0 = 0.f, a1 = 0.f, a2 = 0.f;
      pair_acc(c00a, c00b, wb0*wg0, fr, a0, a1, a2);
      pair_acc(c01a, c01b, wb0*wg1, fr, a0, a1, a2);
      pair_acc(c10a, c10b, wb1*wg0, fr, a0, a1, a2);
      pair_acc(c11a, c11b, wb1*wg1, fr, a0, a1, a2);
      rp[j] = a0*scale + offc + r;
      gp[j] = a1*scale + offc + g;
      bp[j] = a2*scale + offc + b;
    }
    ((float4*)ob)[v]           = ro;
    ((float4*)(ob + NPX))[v]   = go;
    ((float4*)(ob + 2*NPX))[v] = bo;
  }
}

// ---------------- launcher ----------------
extern "C" void kernel_launch(void* const* d_in, const int* in_sizes, int n_in,
                              void* d_out, int out_size, void* d_ws, size_t ws_size,
                              hipStream_t stream) {
  const float* img     = (const float*)d_in[0];
  const float* img_org = (const float*)d_in[1];
  const float* c0w = (const float*)d_in[2];  const float* c0b = (const float*)d_in[3];
  const float* c1w = (const float*)d_in[4];  const float* c1b = (const float*)d_in[5];
  const float* c2w = (const float*)d_in[6];  const float* c2b = (const float*)d_in[7];
  const float* c3w = (const float*)d_in[8];  const float* c3b = (const float*)d_in[9];
  const float* c4w = (const float*)d_in[10]; const float* c4b = (const float*)d_in[11];
  const float* n0g = (const float*)d_in[12]; const float* n0b = (const float*)d_in[13];
  const float* n1g = (const float*)d_in[14]; const float* n1b = (const float*)d_in[15];
  const float* n2g = (const float*)d_in[16]; const float* n2b = (const float*)d_in[17];
  const float* n3g = (const float*)d_in[18]; const float* n3b = (const float*)d_in[19];
  const float* cls0_w = (const float*)d_in[20]; const float* cls0_b = (const float*)d_in[21];
  const float* cls1_w = (const float*)d_in[22]; const float* cls1_b = (const float*)d_in[23];
  const float* s_layers = (const float*)d_in[24];
  const float* w_layers = (const float*)d_in[25];
  const float* luts     = (const float*)d_in[26];
  float* ws = (float*)d_ws;
  float* out = (float*)d_out;

  // zero stats + featsum + maxbuf
  zero_k<<<20, 256, 0, stream>>>(ws + OFF_STATB, 4872);

  // conv0: fp32 (CIN=3). TH=4 OCG=16 PX=8 OCT=2, BLK=512, grid 256
  conv_f32_first<3,16,256,256, 4,16, 8,2, 512><<<256, 512, 0, stream>>>(
      img, c0w, c0b, ws + OFF_Y0, ws + OFF_STAT0);
  // conv1-4: fp16 channel-pair dot2, geometry identical to round-13
  conv_h2<16,32,128,128, 2,32, 4,2, 512, 1, 16384><<<256, 512, 0, stream>>>(
      ws + OFF_Y0, c1w, c1b, ws + OFF_STAT0, n0g, n0b, ws + OFF_Y1, ws + OFF_STAT1);
  conv_h2<32,64,64,64, 2,32, 2,2, 512, 1, 4096><<<256, 512, 0, stream>>>(
      ws + OFF_Y1, c2w, c2b, ws + OFF_STAT1, n1g, n1b, ws + OFF_Y2, ws + OFF_STAT2);
  conv_h2<64,128,32,32, 2,32, 1,2, 512, 1, 1024><<<256, 512, 0, stream>>>(
      ws + OFF_Y2, c3w, c3b, ws + OFF_STAT2, n2g, n2b, ws + OFF_Y3, ws + OFF_STAT3);
  conv_h2<128,128,16,16, 2,16, 1,1, 256, 2, 256><<<256, 256, 0, stream>>>(
      ws + OFF_Y3, c4w, c4b, ws + OFF_STAT3, n3g, n3b, nullptr, ws + OFF_FEATS);

  // U directly from luts/wl with in-block head
  u_direct_kernel<<<600, 256, 0, stream>>>(
      ws + OFF_FEATS, cls0_w, cls0_b, cls1_w, cls1_b,
      luts, w_layers, ws + OFF_U);

  // compact fp16 LUT + per-batch absmax
  lutc_max_kernel<<<141*8, 256, 0, stream>>>(
      ws + OFF_U, s_layers, (uint2*)(ws + OFF_LUTC), (unsigned*)(ws + OFF_MAXB));

  // quantize to 3x10-bit codes
  lutq_kernel<<<141*8, 256, 0, stream>>>(
      (const uint2*)(ws + OFF_LUTC), (const unsigned*)(ws + OFF_MAXB),
      (unsigned*)(ws + OFF_LUTQ));

  // trilinear from LDS-resident code table
  trilin_lds_kernel<<<256, 1024, 0, stream>>>(
      img_org, (const unsigned*)(ws + OFF_LUTQ), (const unsigned*)(ws + OFF_MAXB), out);
}

// Round 16
// 190.900 us; speedup vs baseline: 1.2468x; 1.0136x over previous
//
#include <hip/hip_runtime.h>
#include <hip/hip_fp16.h>

typedef _Float16 h2 __attribute__((ext_vector_type(2)));

// ---------------- workspace layout (float offsets) ----------------
// Y buffers now hold h2 channel-pairs (half the bytes; offsets unchanged/over-allocated)
constexpr size_t OFF_Y0    = 0;         // 8*8cp*128*128 h2 = 524288 floats used
constexpr size_t OFF_Y1    = 2097152;   // 8*16cp*64*64 h2
constexpr size_t OFF_Y2    = 3145728;   // 8*32cp*32*32 h2
constexpr size_t OFF_Y3    = 3670016;   // 8*64cp*16*16 h2
constexpr size_t OFF_U     = 3670016 + 65536;  // 8*15*1089 = 130680 (after Y3's used half)
constexpr size_t OFF_LUTC  = 1048576;   // compact fp16: 8*35937 uint2 = 574992 dwords (dead Y0 tail)
constexpr size_t OFF_LUTQ  = 2400000;   // 10-bit codes: 8*35937 dwords = 287496
constexpr size_t OFF_STATB = 4926640;
constexpr size_t OFF_STAT0 = OFF_STATB + 0;     // 8*16*2  = 256
constexpr size_t OFF_STAT1 = OFF_STATB + 256;   // 8*32*2  = 512
constexpr size_t OFF_STAT2 = OFF_STATB + 768;   // 8*64*2  = 1024
constexpr size_t OFF_STAT3 = OFF_STATB + 1792;  // 8*128*2 = 2048
constexpr size_t OFF_FEATS = OFF_STATB + 3840;  // 8*128   = 1024
constexpr size_t OFF_MAXB  = OFF_STATB + 4864;  // 8 per-batch absmax (uint-as-float)

__global__ __launch_bounds__(256) void zero_k(float* __restrict__ p, int n) {
  int i = blockIdx.x*256 + threadIdx.x;
  if (i < n) p[i] = 0.f;
}

// ---------------- conv0: fp32 input (img), h2 channel-pair output ----------------
template<int CIN, int COUT, int HIN, int WIN, int TH, int OCG, int PX, int OCT, int BLK>
__global__ __launch_bounds__(BLK) void conv_f32_first(
    const float* __restrict__ xin, const float* __restrict__ wgt,
    const float* __restrict__ bias,
    h2* __restrict__ yout, float* __restrict__ stat_out)
{
  constexpr int HOUT = HIN/2, WOUT = WIN/2;
  constexpr int SEG  = WOUT + 4;
  constexpr int XROW = 2*SEG;
  constexpr int XPI  = (2*TH+1)*XROW;
  constexpr int NT   = HOUT/TH;
  constexpr int NSTRIP_B = TH*WOUT/PX;
  constexpr int GPT  = OCG/OCT;
  static_assert(BLK == NSTRIP_B*GPT, "thread mapping mismatch");
  static_assert(OCT == 2, "pair write");
  constexpr int R = NSTRIP_B < 64 ? NSTRIP_B : 64;

  __shared__ __align__(16) float xs[CIN*XPI];
  __shared__ float s_sc[CIN], s_sf[CIN];

  const int tid = threadIdx.x;
  const int lin = blockIdx.x;
  const int b = lin & 7;
  const int r2 = lin >> 3;
  const int tile = r2 % NT;
  const int ocb  = r2 / NT;

  if (tid == 0)      { s_sc[0] = 1.f/0.229f; s_sf[0] = -0.485f/0.229f; }
  else if (tid == 1) { s_sc[1] = 1.f/0.224f; s_sf[1] = -0.456f/0.224f; }
  else if (tid == 2) { s_sc[2] = 1.f/0.225f; s_sf[2] = -0.406f/0.225f; }
  __syncthreads();

  const int iy0 = tile*(2*TH) - 1;
  const float* xb_g = xin + (size_t)b*CIN*HIN*WIN;
  for (int e = tid; e < CIN*(2*TH+1)*(WIN+2); e += BLK) {
    int ic  = e / ((2*TH+1)*(WIN+2));
    int rem = e - ic*((2*TH+1)*(WIN+2));
    int rr  = rem / (WIN+2);
    int cc  = rem - rr*(WIN+2);
    int iy = iy0 + rr, ix = cc - 1;
    float v = 0.f;
    if (iy >= 0 && iy < HIN && ix >= 0 && ix < WIN)
      v = s_sc[ic]*xb_g[(size_t)ic*HIN*WIN + iy*WIN + ix] + s_sf[ic];
    int off = (ix & 1) ? (SEG + ((ix+1) >> 1)) : (ix >> 1);
    xs[ic*XPI + rr*XROW + off] = v;
  }
  __syncthreads();

  const int s  = tid % NSTRIP_B;
  const int g  = tid / NSTRIP_B;
  const int r  = s / (WOUT/PX);
  const int c0 = (s % (WOUT/PX)) * PX;
  const int oc0 = ocb*OCG + g*OCT;

  float acc[OCT][PX];
  #pragma unroll
  for (int k = 0; k < OCT; ++k) {
    float bb = bias[oc0+k];
    #pragma unroll
    for (int j = 0; j < PX; ++j) acc[k][j] = bb;
  }

  for (int ic = 0; ic < CIN; ++ic) {
    float wv[OCT][9];
    #pragma unroll
    for (int k = 0; k < OCT; ++k) {
      const float* wp = wgt + ((size_t)(oc0+k)*CIN + ic)*9;
      #pragma unroll
      for (int t = 0; t < 9; ++t) wv[k][t] = wp[t];
    }
    const float* xb = xs + ic*XPI;
    #pragma unroll
    for (int ky = 0; ky < 3; ++ky) {
      const float* rowp = xb + (2*r+ky)*XROW;
      float eb[PX], ob[PX+1];
      static_assert(PX == 8, "conv0 uses PX=8");
      *(float4*)&eb[0] = *(const float4*)(rowp + c0);
      *(float4*)&eb[4] = *(const float4*)(rowp + c0 + 4);
      *(float4*)&ob[0] = *(const float4*)(rowp + SEG + c0);
      *(float4*)&ob[4] = *(const float4*)(rowp + SEG + c0 + 4);
      ob[8] = rowp[SEG + c0 + 8];
      #pragma unroll
      for (int k = 0; k < OCT; ++k) {
        float w0 = wv[k][ky*3], w1 = wv[k][ky*3+1], w2 = wv[k][ky*3+2];
        #pragma unroll
        for (int j = 0; j < PX; ++j)
          acc[k][j] += w0*ob[j] + w1*eb[j] + w2*ob[j+1];
      }
    }
  }

  const int oy = tile*TH + r;
  float ov[OCT][PX];
  float lsum[OCT], lsq[OCT];
  #pragma unroll
  for (int k = 0; k < OCT; ++k) {
    float ls = 0.f, lq = 0.f;
    #pragma unroll
    for (int j = 0; j < PX; ++j) {
      float a = acc[k][j];
      a = a >= 0.f ? a : 0.2f*a;
      ov[k][j] = a; ls += a; lq += a*a;
    }
    lsum[k] = ls; lsq[k] = lq;
  }
  h2 ph[PX];
  #pragma unroll
  for (int j = 0; j < PX; ++j) { ph[j][0] = (_Float16)ov[0][j]; ph[j][1] = (_Float16)ov[1][j]; }
  h2* yp = yout + (((size_t)b*(COUT/2) + (oc0 >> 1))*HOUT + oy)*WOUT + c0;
  *(uint4*)yp       = *(uint4*)&ph[0];
  *(uint4*)(yp + 4) = *(uint4*)&ph[4];

  #pragma unroll
  for (int k = 0; k < OCT; ++k) {
    #pragma unroll
    for (int off = R/2; off > 0; off >>= 1) {
      lsum[k] += __shfl_down(lsum[k], off);
      lsq[k]  += __shfl_down(lsq[k],  off);
    }
  }
  if ((tid & (R-1)) == 0) {
    #pragma unroll
    for (int k = 0; k < OCT; ++k) {
      atomicAdd(&stat_out[(b*COUT + oc0 + k)*2 + 0], lsum[k]);
      atomicAdd(&stat_out[(b*COUT + oc0 + k)*2 + 1], lsq[k]);
    }
  }
}

// ---------------- conv1-4: h2 channel-pair in/out, v_dot2 inner loop ----------------
// MODE: 1 = mid (inorm from raw stats, write h2 y + stats), 2 = last (mean -> featsum)
template<int CIN, int COUT, int HIN, int WIN, int TH, int OCG, int PX, int OCT,
         int BLK, int MODE, int NPXPREV>
__global__ __launch_bounds__(BLK) void conv_h2(
    const h2* __restrict__ xin, const float* __restrict__ wgt,
    const float* __restrict__ bias, const float* __restrict__ stat_in,
    const float* __restrict__ gam, const float* __restrict__ bet,
    h2* __restrict__ yout, float* __restrict__ stat_out)
{
  constexpr int CINH = CIN/2;
  constexpr int HOUT = HIN/2, WOUT = WIN/2;
  constexpr int SEG  = WOUT + 4;          // mult of 4
  constexpr int XROW = 2*SEG;
  constexpr int XPI  = (2*TH+1)*XROW;
  constexpr int NT   = HOUT/TH;
  constexpr int NSTRIP_B = TH*WOUT/PX;
  constexpr int GPT  = OCG/OCT;
  static_assert(BLK == NSTRIP_B*GPT, "thread mapping mismatch");
  static_assert(OCT == 2 || MODE == 2, "pair write needs OCT=2");
  constexpr int R = NSTRIP_B < 64 ? NSTRIP_B : 64;

  __shared__ __align__(16) h2 xs[CINH*XPI];
  __shared__ float s_sc[CIN], s_sf[CIN];

  const int tid = threadIdx.x;
  const int lin = blockIdx.x;
  const int b = lin & 7;
  const int r2 = lin >> 3;
  const int tile = r2 % NT;
  const int ocb  = r2 / NT;

  if (tid < CIN) {
    float S = stat_in[(b*CIN+tid)*2+0], Q = stat_in[(b*CIN+tid)*2+1];
    float mean = S*(1.0f/NPXPREV);
    float var  = Q*(1.0f/NPXPREV) - mean*mean;
    float rstd = rsqrtf(var + 1e-5f);
    float gg = gam[tid], bb = bet[tid];
    s_sc[tid] = gg*rstd;
    s_sf[tid] = bb - mean*gg*rstd;
  }
  __syncthreads();

  const int iy0 = tile*(2*TH) - 1;
  const h2* xb_g = xin + (size_t)b*CINH*HIN*WIN;
  for (int e = tid; e < CINH*(2*TH+1)*(WIN+2); e += BLK) {
    int icp = e / ((2*TH+1)*(WIN+2));
    int rem = e - icp*((2*TH+1)*(WIN+2));
    int rr  = rem / (WIN+2);
    int cc  = rem - rr*(WIN+2);
    int iy = iy0 + rr, ix = cc - 1;
    float v0 = 0.f, v1 = 0.f;
    if (iy >= 0 && iy < HIN && ix >= 0 && ix < WIN) {
      h2 x = xb_g[(size_t)icp*HIN*WIN + iy*WIN + ix];
      int ic0 = 2*icp;
      v0 = s_sc[ic0]  *(float)x[0] + s_sf[ic0];
      v1 = s_sc[ic0+1]*(float)x[1] + s_sf[ic0+1];
    }
    int off = (ix & 1) ? (SEG + ((ix+1) >> 1)) : (ix >> 1);
    h2 p; p[0] = (_Float16)v0; p[1] = (_Float16)v1;
    xs[icp*XPI + rr*XROW + off] = p;
  }
  __syncthreads();

  const int s  = tid % NSTRIP_B;
  const int g  = tid / NSTRIP_B;
  const int r  = s / (WOUT/PX);
  const int c0 = (s % (WOUT/PX)) * PX;
  const int oc0 = ocb*OCG + g*OCT;

  float acc[OCT][PX];
  #pragma unroll
  for (int k = 0; k < OCT; ++k) {
    float bb = bias[oc0+k];
    #pragma unroll
    for (int j = 0; j < PX; ++j) acc[k][j] = bb;
  }

  for (int icp = 0; icp < CINH; ++icp) {
    h2 wv[OCT][9];
    #pragma unroll
    for (int k = 0; k < OCT; ++k) {
      const float* wp0 = wgt + ((size_t)(oc0+k)*CIN + 2*icp)*9;
      const float* wp1 = wp0 + 9;
      #pragma unroll
      for (int t = 0; t < 9; ++t) {
        h2 w; w[0] = (_Float16)wp0[t]; w[1] = (_Float16)wp1[t];
        wv[k][t] = w;
      }
    }
    const h2* xb = xs + icp*XPI;
    #pragma unroll
    for (int ky = 0; ky < 3; ++ky) {
      const h2* rowp = xb + (2*r+ky)*XROW;
      h2 eb[PX], ob[PX+1];
      if constexpr (PX == 4) {
        *(uint4*)&eb[0] = *(const uint4*)(rowp + c0);
        *(uint4*)&ob[0] = *(const uint4*)(rowp + SEG + c0);
        ob[4] = rowp[SEG + c0 + 4];
      } else if constexpr (PX == 2) {
        *(uint2*)&eb[0] = *(const uint2*)(rowp + c0);
        *(uint2*)&ob[0] = *(const uint2*)(rowp + SEG + c0);
        ob[2] = rowp[SEG + c0 + 2];
      } else {
        eb[0] = rowp[c0];
        ob[0] = rowp[SEG + c0];
        ob[1] = rowp[SEG + c0 + 1];
      }
      #pragma unroll
      for (int k = 0; k < OCT; ++k) {
        h2 w0 = wv[k][ky*3], w1 = wv[k][ky*3+1], w2 = wv[k][ky*3+2];
        #pragma unroll
        for (int j = 0; j < PX; ++j) {
          float a = acc[k][j];
          a = __builtin_amdgcn_fdot2(w0, ob[j],   a, false);
          a = __builtin_amdgcn_fdot2(w1, eb[j],   a, false);
          a = __builtin_amdgcn_fdot2(w2, ob[j+1], a, false);
          acc[k][j] = a;
        }
      }
    }
  }

  const int oy = tile*TH + r;
  if constexpr (MODE != 2) {
    float ov[OCT][PX];
    float lsum[OCT], lsq[OCT];
    #pragma unroll
    for (int k = 0; k < OCT; ++k) {
      float ls = 0.f, lq = 0.f;
      #pragma unroll
      for (int j = 0; j < PX; ++j) {
        float a = acc[k][j];
        a = a >= 0.f ? a : 0.2f*a;
        ov[k][j] = a; ls += a; lq += a*a;
      }
      lsum[k] = ls; lsq[k] = lq;
    }
    h2 ph[PX];
    #pragma unroll
    for (int j = 0; j < PX; ++j) { ph[j][0] = (_Float16)ov[0][j]; ph[j][1] = (_Float16)ov[1][j]; }
    h2* yp = yout + (((size_t)b*(COUT/2) + (oc0 >> 1))*HOUT + oy)*WOUT + c0;
    if constexpr (PX == 4) {
      *(uint4*)yp = *(uint4*)&ph[0];
    } else if constexpr (PX == 2) {
      *(uint2*)yp = *(uint2*)&ph[0];
    } else {
      yp[0] = ph[0];
    }
    #pragma unroll
    for (int k = 0; k < OCT; ++k) {
      #pragma unroll
      for (int off = R/2; off > 0; off >>= 1) {
        lsum[k] += __shfl_down(lsum[k], off);
        lsq[k]  += __shfl_down(lsq[k],  off);
      }
    }
    if ((tid & (R-1)) == 0) {
      #pragma unroll
      for (int k = 0; k < OCT; ++k) {
        atomicAdd(&stat_out[(b*COUT + oc0 + k)*2 + 0], lsum[k]);
        atomicAdd(&stat_out[(b*COUT + oc0 + k)*2 + 1], lsq[k]);
      }
    }
  } else {
    float a = acc[0][0];
    a = a >= 0.f ? a : 0.2f*a;
    #pragma unroll
    for (int off = R/2; off > 0; off >>= 1) a += __shfl_down(a, off);
    if ((tid & (R-1)) == 0) atomicAdd(&stat_out[b*COUT + oc0], a);
  }
}

// ---------------- U direct: head (redundant per block) + V fold + U slice ----------------
__global__ __launch_bounds__(256) void u_direct_kernel(
    const float* __restrict__ featsum, const float* __restrict__ w0, const float* __restrict__ b0,
    const float* __restrict__ w1, const float* __restrict__ b1,
    const float* __restrict__ luts, const float* __restrict__ wl, float* __restrict__ U)
{
  __shared__ float sh_h[128];
  __shared__ float sh_w[20];
  __shared__ float sh_v[20];
  const int tid = threadIdx.x;
  const int lin = blockIdx.x;            // bt + 8*(j*5+qb), 600 blocks
  const int bt = lin & 7;
  const int rest = lin >> 3;             // 0..74
  const int j = rest / 5, qb = rest % 5;
  const int s = j / 3, ch = j % 3;

  if (tid < 128) {
    const float* f = featsum + bt*128;
    const float* w = w0 + tid*128;
    float a = 0.f;
    for (int k = 0; k < 128; ++k) a += f[k]*w[k];
    a = b0[tid] + a*(1.0f/64.0f);
    float c = fminf(fmaxf(a + 3.f, 0.f), 6.f);
    sh_h[tid] = a * c * (1.f/6.f);
  }
  __syncthreads();
  if (tid < 20) {
    const float* w = w1 + tid*128;
    float a = b1[tid];
    for (int k = 0; k < 128; ++k) a += sh_h[k]*w[k];
    sh_w[tid] = a;
  }
  __syncthreads();
  if (tid < 20) {
    float a = 0.f;
    #pragma unroll
    for (int n = 0; n < 20; ++n)
      a += sh_w[n] * luts[(s*60 + n*3 + ch)*20 + tid];
    sh_v[tid] = a;
  }
  __syncthreads();
  const int q = qb*256 + tid;
  if (q < 1089) {
    float a = 0.f;
    #pragma unroll
    for (int w = 0; w < 20; ++w) a += sh_v[w] * wl[w*1089 + q];
    U[(size_t)(bt*15 + j)*1089 + q] = a;
  }
}

// ---------------- compact fp16 LUT + per-batch absmax ----------------
__global__ __launch_bounds__(256) void lutc_max_kernel(
    const float* __restrict__ U, const float* __restrict__ slay,
    uint2* __restrict__ lutc, unsigned* __restrict__ maxbuf)
{
  __shared__ float s_slay[165];
  __shared__ unsigned s_max;
  const int tid = threadIdx.x;
  if (tid < 165) s_slay[tid] = slay[tid];
  if (tid == 0) s_max = 0u;
  __syncthreads();
  const int lin = blockIdx.x;            // bt + 8*chunk, 141*8 blocks
  const int bt = lin & 7;
  const int i = (lin >> 3)*256 + tid;
  if (i < 35937) {
    int bi = i / 1089, rem = i - bi*1089, gi = rem / 33, ri = rem - gi*33;
    const float* Ub = U + (size_t)bt*15*1089;
    float v0 = 0.f, v1 = 0.f, v2 = 0.f;
    #pragma unroll
    for (int s = 0; s < 5; ++s) {
      v0 += s_slay[ri*5+s] * Ub[(s*3+0)*1089 + bi*33 + gi];
      v1 += s_slay[gi*5+s] * Ub[(s*3+1)*1089 + bi*33 + ri];
      v2 += s_slay[bi*5+s] * Ub[(s*3+2)*1089 + gi*33 + ri];
    }
    union { __half2 h2v; unsigned u; } p0, p1;
    p0.h2v = __floats2half2_rn(v0, v1);
    p1.h2v = __floats2half2_rn(v2, 0.f);
    lutc[(size_t)bt*35937 + i] = make_uint2(p0.u, p1.u);
    float m = fmaxf(fmaxf(fabsf(v0), fabsf(v1)), fabsf(v2));
    atomicMax(&s_max, __float_as_uint(m));   // nonneg floats: uint cmp == float cmp
  }
  __syncthreads();
  if (tid == 0) atomicMax(&maxbuf[bt], s_max);
}

// ---------------- quantize compact fp16 -> 3x10-bit codes (4B/corner) ----------------
__global__ __launch_bounds__(256) void lutq_kernel(
    const uint2* __restrict__ lutc, const unsigned* __restrict__ maxbuf,
    unsigned* __restrict__ lutq)
{
  const int lin = blockIdx.x;            // bt + 8*chunk, 141*8 blocks
  const int bt = lin & 7;
  const int i = (lin >> 3)*256 + threadIdx.x;
  if (i >= 35937) return;
  float maxv = __uint_as_float(maxbuf[bt]);
  float enc = maxv > 0.f ? 511.0f/maxv : 0.f;
  uint2 c = lutc[(size_t)bt*35937 + i];
  __half2 h01 = *(__half2*)&c.x;
  __half2 h2_ = *(__half2*)&c.y;
  float v0 = __low2float(h01), v1 = __high2float(h01), v2 = __low2float(h2_);
  int q0 = (int)rintf(v0*enc) + 512;
  int q1 = (int)rintf(v1*enc) + 512;
  int q2 = (int)rintf(v2*enc) + 512;
  q0 = q0 < 0 ? 0 : (q0 > 1023 ? 1023 : q0);
  q1 = q1 < 0 ? 0 : (q1 > 1023 ? 1023 : q1);
  q2 = q2 < 0 ? 0 : (q2 > 1023 ? 1023 : q2);
  lutq[(size_t)bt*35937 + i] = (unsigned)q0 | ((unsigned)q1 << 10) | ((unsigned)q2 << 20);
}

// ---------------- trilinear from LDS-resident quantized LUT + residual ----------------
__device__ __forceinline__ void pair_acc(unsigned ca, unsigned cb, float wp, float fr,
                                         float& a0, float& a1, float& a2)
{
  float q0a = (float)(ca & 1023u), q1a = (float)((ca >> 10) & 1023u), q2a = (float)((ca >> 20) & 1023u);
  float q0b = (float)(cb & 1023u), q1b = (float)((cb >> 10) & 1023u), q2b = (float)((cb >> 20) & 1023u);
  a0 += wp * (q0a + fr*(q0b - q0a));
  a1 += wp * (q1a + fr*(q1b - q1a));
  a2 += wp * (q2a + fr*(q2b - q2a));
}

__global__ __launch_bounds__(1024) void trilin_lds_kernel(
    const float* __restrict__ img, const unsigned* __restrict__ lutq,
    const unsigned* __restrict__ maxbuf, float* __restrict__ out)
{
  constexpr int NPX = 720*1280;
  constexpr int NV4 = NPX/4;            // 230400
  constexpr int PER_BLK = NV4/32;       // 7200 float4-groups per block
  __shared__ unsigned s_lut[35937];     // 143,748 B

  const int tid = threadIdx.x;
  const int lin = blockIdx.x;           // bt + 8*bb, 256 blocks
  const int bt = lin & 7;
  const int bb = lin >> 3;              // 0..31
  const unsigned* Lg = lutq + (size_t)bt*35937;
  for (int i = tid; i < 35937; i += 1024) s_lut[i] = Lg[i];
  __syncthreads();

  const float maxv  = __uint_as_float(maxbuf[bt]);
  const float scale = maxv * (1.0f/511.0f);
  const float offc  = -512.0f * scale;
  const float* ib = img + (size_t)bt*3*NPX;
  float* ob = out + (size_t)bt*3*NPX;
  const float invbin = 32.0f/1.000001f;
  const int vend = bb*PER_BLK + PER_BLK;

  for (int v = bb*PER_BLK + tid; v < vend; v += 1024) {
    float4 r4 = ((const float4*)ib)[v];
    float4 g4 = ((const float4*)(ib + NPX))[v];
    float4 b4 = ((const float4*)(ib + 2*NPX))[v];
    float4 ro, go, bo;
    float* rp = (float*)&ro; float* gp = (float*)&go; float* bp = (float*)&bo;
    #pragma unroll
    for (int j = 0; j < 4; ++j) {
      float r = ((float*)&r4)[j], g = ((float*)&g4)[j], b = ((float*)&b4)[j];
      float pr = r*invbin, pg = g*invbin, pb = b*invbin;
      int ri = (int)pr; ri = ri > 31 ? 31 : ri; ri = ri < 0 ? 0 : ri;
      int gi = (int)pg; gi = gi > 31 ? 31 : gi; gi = gi < 0 ? 0 : gi;
      int bi = (int)pb; bi = bi > 31 ? 31 : bi; bi = bi < 0 ? 0 : bi;
      float fr = pr - ri, fg = pg - gi, fb = pb - bi;
      int i00 = (bi*33 + gi)*33 + ri;
      unsigned c00a = s_lut[i00],        c00b = s_lut[i00 + 1];
      unsigned c01a = s_lut[i00 + 33],   c01b = s_lut[i00 + 34];
      unsigned c10a = s_lut[i00 + 1089], c10b = s_lut[i00 + 1090];
      unsigned c11a = s_lut[i00 + 1122], c11b = s_lut[i00 + 1123];
      float wb0 = 1.f - fb, wb1 = fb, wg0 = 1.f - fg, wg1 = fg;
      float a0 = 0.f, a1 = 0.f, a2 = 0.f;
      pair_acc(c00a, c00b, wb0*wg0, fr, a0, a1, a2);
      pair_acc(c01a, c01b, wb0*wg1, fr, a0, a1, a2);
      pair_acc(c10a, c10b, wb1*wg0, fr, a0, a1, a2);
      pair_acc(c11a, c11b, wb1*wg1, fr, a0, a1, a2);
      rp[j] = a0*scale + offc + r;
      gp[j] = a1*scale + offc + g;
      bp[j] = a2*scale + offc + b;
    }
    ((float4*)ob)[v]           = ro;
    ((float4*)(ob + NPX))[v]   = go;
    ((float4*)(ob + 2*NPX))[v] = bo;
  }
}

// ---------------- launcher ----------------
extern "C" void kernel_launch(void* const* d_in, const int* in_sizes, int n_in,
                              void* d_out, int out_size, void* d_ws, size_t ws_size,
                              hipStream_t stream) {
  const float* img     = (const float*)d_in[0];
  const float* img_org = (const float*)d_in[1];
  const float* c0w = (const float*)d_in[2];  const float* c0b = (const float*)d_in[3];
  const float* c1w = (const float*)d_in[4];  const float* c1b = (const float*)d_in[5];
  const float* c2w = (const float*)d_in[6];  const float* c2b = (const float*)d_in[7];
  const float* c3w = (const float*)d_in[8];  const float* c3b = (const float*)d_in[9];
  const float* c4w = (const float*)d_in[10]; const float* c4b = (const float*)d_in[11];
  const float* n0g = (const float*)d_in[12]; const float* n0b = (const float*)d_in[13];
  const float* n1g = (const float*)d_in[14]; const float* n1b = (const float*)d_in[15];
  const float* n2g = (const float*)d_in[16]; const float* n2b = (const float*)d_in[17];
  const float* n3g = (const float*)d_in[18]; const float* n3b = (const float*)d_in[19];
  const float* cls0_w = (const float*)d_in[20]; const float* cls0_b = (const float*)d_in[21];
  const float* cls1_w = (const float*)d_in[22]; const float* cls1_b = (const float*)d_in[23];
  const float* s_layers = (const float*)d_in[24];
  const float* w_layers = (const float*)d_in[25];
  const float* luts     = (const float*)d_in[26];
  float* ws = (float*)d_ws;
  float* out = (float*)d_out;

  // zero stats + featsum + maxbuf
  zero_k<<<20, 256, 0, stream>>>(ws + OFF_STATB, 4872);

  // conv0: fp32 input, h2 output. TH=4 OCG=16 PX=8 OCT=2, BLK=512, grid 256
  conv_f32_first<3,16,256,256, 4,16, 8,2, 512><<<256, 512, 0, stream>>>(
      img, c0w, c0b, (h2*)(ws + OFF_Y0), ws + OFF_STAT0);
  // conv1-4: h2 in/out, dot2 inner loop, round-13 geometry
  conv_h2<16,32,128,128, 2,32, 4,2, 512, 1, 16384><<<256, 512, 0, stream>>>(
      (const h2*)(ws + OFF_Y0), c1w, c1b, ws + OFF_STAT0, n0g, n0b,
      (h2*)(ws + OFF_Y1), ws + OFF_STAT1);
  conv_h2<32,64,64,64, 2,32, 2,2, 512, 1, 4096><<<256, 512, 0, stream>>>(
      (const h2*)(ws + OFF_Y1), c2w, c2b, ws + OFF_STAT1, n1g, n1b,
      (h2*)(ws + OFF_Y2), ws + OFF_STAT2);
  conv_h2<64,128,32,32, 2,32, 1,2, 512, 1, 1024><<<256, 512, 0, stream>>>(
      (const h2*)(ws + OFF_Y2), c3w, c3b, ws + OFF_STAT2, n2g, n2b,
      (h2*)(ws + OFF_Y3), ws + OFF_STAT3);
  conv_h2<128,128,16,16, 2,16, 1,1, 256, 2, 256><<<256, 256, 0, stream>>>(
      (const h2*)(ws + OFF_Y3), c4w, c4b, ws + OFF_STAT3, n3g, n3b,
      nullptr, ws + OFF_FEATS);

  // U directly from luts/wl with in-block head
  u_direct_kernel<<<600, 256, 0, stream>>>(
      ws + OFF_FEATS, cls0_w, cls0_b, cls1_w, cls1_b,
      luts, w_layers, ws + OFF_U);

  // compact fp16 LUT + per-batch absmax
  lutc_max_kernel<<<141*8, 256, 0, stream>>>(
      ws + OFF_U, s_layers, (uint2*)(ws + OFF_LUTC), (unsigned*)(ws + OFF_MAXB));

  // quantize to 3x10-bit codes
  lutq_kernel<<<141*8, 256, 0, stream>>>(
      (const uint2*)(ws + OFF_LUTC), (const unsigned*)(ws + OFF_MAXB),
      (unsigned*)(ws + OFF_LUTQ));

  // trilinear from LDS-resident code table
  trilin_lds_kernel<<<256, 1024, 0, stream>>>(
      img_org, (const unsigned*)(ws + OFF_LUTQ), (const unsigned*)(ws + OFF_MAXB), out);
}

// Round 17
// 178.448 us; speedup vs baseline: 1.3338x; 1.0698x over previous
//
#include <hip/hip_runtime.h>
#include <hip/hip_fp16.h>

typedef _Float16 h2 __attribute__((ext_vector_type(2)));

// ---------------- workspace layout (float offsets) ----------------
constexpr size_t OFF_Y0    = 0;         // h2 activations (half-size)
constexpr size_t OFF_Y1    = 2097152;
constexpr size_t OFF_Y2    = 3145728;
constexpr size_t OFF_Y3    = 3670016;
constexpr size_t OFF_U     = 3670016 + 65536;  // 8*15*1089 = 130680
constexpr size_t OFF_LUTC  = 1048576;   // compact fp16: 8*35937 uint2
constexpr size_t OFF_LUTQ  = 2400000;   // 10-bit codes: 8*35937 dwords
constexpr size_t OFF_STATB = 4926640;
constexpr size_t OFF_STAT0 = OFF_STATB + 0;
constexpr size_t OFF_STAT1 = OFF_STATB + 256;
constexpr size_t OFF_STAT2 = OFF_STATB + 768;
constexpr size_t OFF_STAT3 = OFF_STATB + 1792;
constexpr size_t OFF_FEATS = OFF_STATB + 3840;
constexpr size_t OFF_MAXB  = OFF_STATB + 4864;

__global__ __launch_bounds__(256) void zero_k(float* __restrict__ p, int n) {
  int i = blockIdx.x*256 + threadIdx.x;
  if (i < n) p[i] = 0.f;
}

// ---------------- conv0: fp32 input (img), h2 pair output; weights LDS-staged ----------------
template<int CIN, int COUT, int HIN, int WIN, int TH, int OCG, int PX, int OCT, int BLK>
__global__ __launch_bounds__(BLK) void conv_f32_first(
    const float* __restrict__ xin, const float* __restrict__ wgt,
    const float* __restrict__ bias,
    h2* __restrict__ yout, float* __restrict__ stat_out)
{
  constexpr int HOUT = HIN/2, WOUT = WIN/2;
  constexpr int SEG  = WOUT + 4;
  constexpr int XROW = 2*SEG;
  constexpr int XPI  = (2*TH+1)*XROW;
  constexpr int NT   = HOUT/TH;
  constexpr int NSTRIP_B = TH*WOUT/PX;
  constexpr int GPT  = OCG/OCT;
  static_assert(BLK == NSTRIP_B*GPT, "thread mapping mismatch");
  static_assert(OCT == 2, "pair write");
  constexpr int R = NSTRIP_B < 64 ? NSTRIP_B : 64;

  __shared__ __align__(16) float xs[CIN*XPI];
  __shared__ float s_w[CIN*9*OCG];
  __shared__ float s_sc[CIN], s_sf[CIN];

  const int tid = threadIdx.x;
  const int lin = blockIdx.x;
  const int b = lin & 7;
  const int r2 = lin >> 3;
  const int tile = r2 % NT;
  const int ocb  = r2 / NT;

  if (tid == 0)      { s_sc[0] = 1.f/0.229f; s_sf[0] = -0.485f/0.229f; }
  else if (tid == 1) { s_sc[1] = 1.f/0.224f; s_sf[1] = -0.456f/0.224f; }
  else if (tid == 2) { s_sc[2] = 1.f/0.225f; s_sf[2] = -0.406f/0.225f; }
  __syncthreads();

  // stage weights: s_w[(ic*9+t)*OCG + ocl]
  for (int e = tid; e < OCG*CIN*9; e += BLK) {
    int ocl = e / (CIN*9);
    int rem = e - ocl*(CIN*9);
    int ic = rem / 9, t = rem - ic*9;
    s_w[(ic*9 + t)*OCG + ocl] = wgt[((size_t)(ocb*OCG + ocl)*CIN + ic)*9 + t];
  }

  const int iy0 = tile*(2*TH) - 1;
  const float* xb_g = xin + (size_t)b*CIN*HIN*WIN;
  for (int e = tid; e < CIN*(2*TH+1)*(WIN+2); e += BLK) {
    int ic  = e / ((2*TH+1)*(WIN+2));
    int rem = e - ic*((2*TH+1)*(WIN+2));
    int rr  = rem / (WIN+2);
    int cc  = rem - rr*(WIN+2);
    int iy = iy0 + rr, ix = cc - 1;
    float v = 0.f;
    if (iy >= 0 && iy < HIN && ix >= 0 && ix < WIN)
      v = s_sc[ic]*xb_g[(size_t)ic*HIN*WIN + iy*WIN + ix] + s_sf[ic];
    int off = (ix & 1) ? (SEG + ((ix+1) >> 1)) : (ix >> 1);
    xs[ic*XPI + rr*XROW + off] = v;
  }
  __syncthreads();

  const int s  = tid % NSTRIP_B;
  const int g  = tid / NSTRIP_B;
  const int r  = s / (WOUT/PX);
  const int c0 = (s % (WOUT/PX)) * PX;
  const int oc0 = ocb*OCG + g*OCT;

  float acc[OCT][PX];
  #pragma unroll
  for (int k = 0; k < OCT; ++k) {
    float bb = bias[oc0+k];
    #pragma unroll
    for (int j = 0; j < PX; ++j) acc[k][j] = bb;
  }

  for (int ic = 0; ic < CIN; ++ic) {
    float wv[OCT][9];
    #pragma unroll
    for (int t = 0; t < 9; ++t) {
      #pragma unroll
      for (int k = 0; k < OCT; ++k)
        wv[k][t] = s_w[(ic*9 + t)*OCG + g*OCT + k];
    }
    const float* xb = xs + ic*XPI;
    #pragma unroll
    for (int ky = 0; ky < 3; ++ky) {
      const float* rowp = xb + (2*r+ky)*XROW;
      float eb[PX], ob[PX+1];
      static_assert(PX == 8, "conv0 uses PX=8");
      *(float4*)&eb[0] = *(const float4*)(rowp + c0);
      *(float4*)&eb[4] = *(const float4*)(rowp + c0 + 4);
      *(float4*)&ob[0] = *(const float4*)(rowp + SEG + c0);
      *(float4*)&ob[4] = *(const float4*)(rowp + SEG + c0 + 4);
      ob[8] = rowp[SEG + c0 + 8];
      #pragma unroll
      for (int k = 0; k < OCT; ++k) {
        float w0 = wv[k][ky*3], w1 = wv[k][ky*3+1], w2 = wv[k][ky*3+2];
        #pragma unroll
        for (int j = 0; j < PX; ++j)
          acc[k][j] += w0*ob[j] + w1*eb[j] + w2*ob[j+1];
      }
    }
  }

  const int oy = tile*TH + r;
  float ov[OCT][PX];
  float lsum[OCT], lsq[OCT];
  #pragma unroll
  for (int k = 0; k < OCT; ++k) {
    float ls = 0.f, lq = 0.f;
    #pragma unroll
    for (int j = 0; j < PX; ++j) {
      float a = acc[k][j];
      a = a >= 0.f ? a : 0.2f*a;
      ov[k][j] = a; ls += a; lq += a*a;
    }
    lsum[k] = ls; lsq[k] = lq;
  }
  h2 ph[PX];
  #pragma unroll
  for (int j = 0; j < PX; ++j) { ph[j][0] = (_Float16)ov[0][j]; ph[j][1] = (_Float16)ov[1][j]; }
  h2* yp = yout + (((size_t)b*(COUT/2) + (oc0 >> 1))*HOUT + oy)*WOUT + c0;
  *(uint4*)yp       = *(uint4*)&ph[0];
  *(uint4*)(yp + 4) = *(uint4*)&ph[4];

  #pragma unroll
  for (int k = 0; k < OCT; ++k) {
    #pragma unroll
    for (int off = R/2; off > 0; off >>= 1) {
      lsum[k] += __shfl_down(lsum[k], off);
      lsq[k]  += __shfl_down(lsq[k],  off);
    }
  }
  if ((tid & (R-1)) == 0) {
    #pragma unroll
    for (int k = 0; k < OCT; ++k) {
      atomicAdd(&stat_out[(b*COUT + oc0 + k)*2 + 0], lsum[k]);
      atomicAdd(&stat_out[(b*COUT + oc0 + k)*2 + 1], lsq[k]);
    }
  }
}

// ---------------- conv1-4: h2 in/out, v_dot2, weights LDS-staged as h2 pairs ----------------
// MODE: 1 = mid (inorm from raw stats, write h2 y + stats), 2 = last (mean -> featsum)
template<int CIN, int COUT, int HIN, int WIN, int TH, int OCG, int PX, int OCT,
         int BLK, int MODE, int NPXPREV>
__global__ __launch_bounds__(BLK) void conv_h2(
    const h2* __restrict__ xin, const float* __restrict__ wgt,
    const float* __restrict__ bias, const float* __restrict__ stat_in,
    const float* __restrict__ gam, const float* __restrict__ bet,
    h2* __restrict__ yout, float* __restrict__ stat_out)
{
  constexpr int CINH = CIN/2;
  constexpr int HOUT = HIN/2, WOUT = WIN/2;
  constexpr int SEG  = WOUT + 4;
  constexpr int XROW = 2*SEG;
  constexpr int XPI  = (2*TH+1)*XROW;
  constexpr int NT   = HOUT/TH;
  constexpr int NSTRIP_B = TH*WOUT/PX;
  constexpr int GPT  = OCG/OCT;
  static_assert(BLK == NSTRIP_B*GPT, "thread mapping mismatch");
  static_assert(OCT == 2 || MODE == 2, "pair write needs OCT=2");
  constexpr int R = NSTRIP_B < 64 ? NSTRIP_B : 64;

  __shared__ __align__(16) h2 xs[CINH*XPI];
  __shared__ h2 s_w[CINH*9*OCG];
  __shared__ float s_sc[CIN], s_sf[CIN];

  const int tid = threadIdx.x;
  const int lin = blockIdx.x;
  const int b = lin & 7;
  const int r2 = lin >> 3;
  const int tile = r2 % NT;
  const int ocb  = r2 / NT;

  if (tid < CIN) {
    float S = stat_in[(b*CIN+tid)*2+0], Q = stat_in[(b*CIN+tid)*2+1];
    float mean = S*(1.0f/NPXPREV);
    float var  = Q*(1.0f/NPXPREV) - mean*mean;
    float rstd = rsqrtf(var + 1e-5f);
    float gg = gam[tid], bb = bet[tid];
    s_sc[tid] = gg*rstd;
    s_sf[tid] = bb - mean*gg*rstd;
  }
  __syncthreads();

  // stage weights as h2 channel-pairs: s_w[(icp*9+t)*OCG + ocl]
  for (int e = tid; e < OCG*CINH*9; e += BLK) {
    int ocl = e / (CINH*9);
    int rem = e - ocl*(CINH*9);
    int icp = rem / 9, t = rem - icp*9;
    const float* wp = wgt + ((size_t)(ocb*OCG + ocl)*CIN + 2*icp)*9 + t;
    h2 w; w[0] = (_Float16)wp[0]; w[1] = (_Float16)wp[9];
    s_w[(icp*9 + t)*OCG + ocl] = w;
  }

  const int iy0 = tile*(2*TH) - 1;
  const h2* xb_g = xin + (size_t)b*CINH*HIN*WIN;
  for (int e = tid; e < CINH*(2*TH+1)*(WIN+2); e += BLK) {
    int icp = e / ((2*TH+1)*(WIN+2));
    int rem = e - icp*((2*TH+1)*(WIN+2));
    int rr  = rem / (WIN+2);
    int cc  = rem - rr*(WIN+2);
    int iy = iy0 + rr, ix = cc - 1;
    float v0 = 0.f, v1 = 0.f;
    if (iy >= 0 && iy < HIN && ix >= 0 && ix < WIN) {
      h2 x = xb_g[(size_t)icp*HIN*WIN + iy*WIN + ix];
      int ic0 = 2*icp;
      v0 = s_sc[ic0]  *(float)x[0] + s_sf[ic0];
      v1 = s_sc[ic0+1]*(float)x[1] + s_sf[ic0+1];
    }
    int off = (ix & 1) ? (SEG + ((ix+1) >> 1)) : (ix >> 1);
    h2 p; p[0] = (_Float16)v0; p[1] = (_Float16)v1;
    xs[icp*XPI + rr*XROW + off] = p;
  }
  __syncthreads();

  const int s  = tid % NSTRIP_B;
  const int g  = tid / NSTRIP_B;
  const int r  = s / (WOUT/PX);
  const int c0 = (s % (WOUT/PX)) * PX;
  const int oc0 = ocb*OCG + g*OCT;

  float acc[OCT][PX];
  #pragma unroll
  for (int k = 0; k < OCT; ++k) {
    float bb = bias[oc0+k];
    #pragma unroll
    for (int j = 0; j < PX; ++j) acc[k][j] = bb;
  }

  for (int icp = 0; icp < CINH; ++icp) {
    h2 wv[OCT][9];
    #pragma unroll
    for (int t = 0; t < 9; ++t) {
      #pragma unroll
      for (int k = 0; k < OCT; ++k)
        wv[k][t] = s_w[(icp*9 + t)*OCG + g*OCT + k];
    }
    const h2* xb = xs + icp*XPI;
    #pragma unroll
    for (int ky = 0; ky < 3; ++ky) {
      const h2* rowp = xb + (2*r+ky)*XROW;
      h2 eb[PX], ob[PX+1];
      if constexpr (PX == 4) {
        *(uint4*)&eb[0] = *(const uint4*)(rowp + c0);
        *(uint4*)&ob[0] = *(const uint4*)(rowp + SEG + c0);
        ob[4] = rowp[SEG + c0 + 4];
      } else if constexpr (PX == 2) {
        *(uint2*)&eb[0] = *(const uint2*)(rowp + c0);
        *(uint2*)&ob[0] = *(const uint2*)(rowp + SEG + c0);
        ob[2] = rowp[SEG + c0 + 2];
      } else {
        eb[0] = rowp[c0];
        ob[0] = rowp[SEG + c0];
        ob[1] = rowp[SEG + c0 + 1];
      }
      #pragma unroll
      for (int k = 0; k < OCT; ++k) {
        h2 w0 = wv[k][ky*3], w1 = wv[k][ky*3+1], w2 = wv[k][ky*3+2];
        #pragma unroll
        for (int j = 0; j < PX; ++j) {
          float a = acc[k][j];
          a = __builtin_amdgcn_fdot2(w0, ob[j],   a, false);
          a = __builtin_amdgcn_fdot2(w1, eb[j],   a, false);
          a = __builtin_amdgcn_fdot2(w2, ob[j+1], a, false);
          acc[k][j] = a;
        }
      }
    }
  }

  const int oy = tile*TH + r;
  if constexpr (MODE != 2) {
    float ov[OCT][PX];
    float lsum[OCT], lsq[OCT];
    #pragma unroll
    for (int k = 0; k < OCT; ++k) {
      float ls = 0.f, lq = 0.f;
      #pragma unroll
      for (int j = 0; j < PX; ++j) {
        float a = acc[k][j];
        a = a >= 0.f ? a : 0.2f*a;
        ov[k][j] = a; ls += a; lq += a*a;
      }
      lsum[k] = ls; lsq[k] = lq;
    }
    h2 ph[PX];
    #pragma unroll
    for (int j = 0; j < PX; ++j) { ph[j][0] = (_Float16)ov[0][j]; ph[j][1] = (_Float16)ov[1][j]; }
    h2* yp = yout + (((size_t)b*(COUT/2) + (oc0 >> 1))*HOUT + oy)*WOUT + c0;
    if constexpr (PX == 4) {
      *(uint4*)yp = *(uint4*)&ph[0];
    } else if constexpr (PX == 2) {
      *(uint2*)yp = *(uint2*)&ph[0];
    } else {
      yp[0] = ph[0];
    }
    #pragma unroll
    for (int k = 0; k < OCT; ++k) {
      #pragma unroll
      for (int off = R/2; off > 0; off >>= 1) {
        lsum[k] += __shfl_down(lsum[k], off);
        lsq[k]  += __shfl_down(lsq[k],  off);
      }
    }
    if ((tid & (R-1)) == 0) {
      #pragma unroll
      for (int k = 0; k < OCT; ++k) {
        atomicAdd(&stat_out[(b*COUT + oc0 + k)*2 + 0], lsum[k]);
        atomicAdd(&stat_out[(b*COUT + oc0 + k)*2 + 1], lsq[k]);
      }
    }
  } else {
    float a = acc[0][0];
    a = a >= 0.f ? a : 0.2f*a;
    #pragma unroll
    for (int off = R/2; off > 0; off >>= 1) a += __shfl_down(a, off);
    if ((tid & (R-1)) == 0) atomicAdd(&stat_out[b*COUT + oc0], a);
  }
}

// ---------------- U direct: head (redundant per block) + V fold + U slice ----------------
__global__ __launch_bounds__(256) void u_direct_kernel(
    const float* __restrict__ featsum, const float* __restrict__ w0, const float* __restrict__ b0,
    const float* __restrict__ w1, const float* __restrict__ b1,
    const float* __restrict__ luts, const float* __restrict__ wl, float* __restrict__ U)
{
  __shared__ float sh_h[128];
  __shared__ float sh_w[20];
  __shared__ float sh_v[20];
  const int tid = threadIdx.x;
  const int lin = blockIdx.x;            // bt + 8*(j*5+qb), 600 blocks
  const int bt = lin & 7;
  const int rest = lin >> 3;             // 0..74
  const int j = rest / 5, qb = rest % 5;
  const int s = j / 3, ch = j % 3;

  if (tid < 128) {
    const float* f = featsum + bt*128;
    const float* w = w0 + tid*128;
    float a = 0.f;
    for (int k = 0; k < 128; ++k) a += f[k]*w[k];
    a = b0[tid] + a*(1.0f/64.0f);
    float c = fminf(fmaxf(a + 3.f, 0.f), 6.f);
    sh_h[tid] = a * c * (1.f/6.f);
  }
  __syncthreads();
  if (tid < 20) {
    const float* w = w1 + tid*128;
    float a = b1[tid];
    for (int k = 0; k < 128; ++k) a += sh_h[k]*w[k];
    sh_w[tid] = a;
  }
  __syncthreads();
  if (tid < 20) {
    float a = 0.f;
    #pragma unroll
    for (int n = 0; n < 20; ++n)
      a += sh_w[n] * luts[(s*60 + n*3 + ch)*20 + tid];
    sh_v[tid] = a;
  }
  __syncthreads();
  const int q = qb*256 + tid;
  if (q < 1089) {
    float a = 0.f;
    #pragma unroll
    for (int w = 0; w < 20; ++w) a += sh_v[w] * wl[w*1089 + q];
    U[(size_t)(bt*15 + j)*1089 + q] = a;
  }
}

// ---------------- compact fp16 LUT + per-batch absmax ----------------
__global__ __launch_bounds__(256) void lutc_max_kernel(
    const float* __restrict__ U, const float* __restrict__ slay,
    uint2* __restrict__ lutc, unsigned* __restrict__ maxbuf)
{
  __shared__ float s_slay[165];
  __shared__ unsigned s_max;
  const int tid = threadIdx.x;
  if (tid < 165) s_slay[tid] = slay[tid];
  if (tid == 0) s_max = 0u;
  __syncthreads();
  const int lin = blockIdx.x;            // bt + 8*chunk, 141*8 blocks
  const int bt = lin & 7;
  const int i = (lin >> 3)*256 + tid;
  if (i < 35937) {
    int bi = i / 1089, rem = i - bi*1089, gi = rem / 33, ri = rem - gi*33;
    const float* Ub = U + (size_t)bt*15*1089;
    float v0 = 0.f, v1 = 0.f, v2 = 0.f;
    #pragma unroll
    for (int s = 0; s < 5; ++s) {
      v0 += s_slay[ri*5+s] * Ub[(s*3+0)*1089 + bi*33 + gi];
      v1 += s_slay[gi*5+s] * Ub[(s*3+1)*1089 + bi*33 + ri];
      v2 += s_slay[bi*5+s] * Ub[(s*3+2)*1089 + gi*33 + ri];
    }
    union { __half2 h2v; unsigned u; } p0, p1;
    p0.h2v = __floats2half2_rn(v0, v1);
    p1.h2v = __floats2half2_rn(v2, 0.f);
    lutc[(size_t)bt*35937 + i] = make_uint2(p0.u, p1.u);
    float m = fmaxf(fmaxf(fabsf(v0), fabsf(v1)), fabsf(v2));
    atomicMax(&s_max, __float_as_uint(m));   // nonneg floats: uint cmp == float cmp
  }
  __syncthreads();
  if (tid == 0) atomicMax(&maxbuf[bt], s_max);
}

// ---------------- quantize compact fp16 -> 3x10-bit codes (4B/corner) ----------------
__global__ __launch_bounds__(256) void lutq_kernel(
    const uint2* __restrict__ lutc, const unsigned* __restrict__ maxbuf,
    unsigned* __restrict__ lutq)
{
  const int lin = blockIdx.x;            // bt + 8*chunk, 141*8 blocks
  const int bt = lin & 7;
  const int i = (lin >> 3)*256 + threadIdx.x;
  if (i >= 35937) return;
  float maxv = __uint_as_float(maxbuf[bt]);
  float enc = maxv > 0.f ? 511.0f/maxv : 0.f;
  uint2 c = lutc[(size_t)bt*35937 + i];
  __half2 h01 = *(__half2*)&c.x;
  __half2 h2_ = *(__half2*)&c.y;
  float v0 = __low2float(h01), v1 = __high2float(h01), v2 = __low2float(h2_);
  int q0 = (int)rintf(v0*enc) + 512;
  int q1 = (int)rintf(v1*enc) + 512;
  int q2 = (int)rintf(v2*enc) + 512;
  q0 = q0 < 0 ? 0 : (q0 > 1023 ? 1023 : q0);
  q1 = q1 < 0 ? 0 : (q1 > 1023 ? 1023 : q1);
  q2 = q2 < 0 ? 0 : (q2 > 1023 ? 1023 : q2);
  lutq[(size_t)bt*35937 + i] = (unsigned)q0 | ((unsigned)q1 << 10) | ((unsigned)q2 << 20);
}

// ---------------- trilinear from LDS-resident quantized LUT + residual ----------------
__device__ __forceinline__ void pair_acc(unsigned ca, unsigned cb, float wp, float fr,
                                         float& a0, float& a1, float& a2)
{
  float q0a = (float)(ca & 1023u), q1a = (float)((ca >> 10) & 1023u), q2a = (float)((ca >> 20) & 1023u);
  float q0b = (float)(cb & 1023u), q1b = (float)((cb >> 10) & 1023u), q2b = (float)((cb >> 20) & 1023u);
  a0 += wp * (q0a + fr*(q0b - q0a));
  a1 += wp * (q1a + fr*(q1b - q1a));
  a2 += wp * (q2a + fr*(q2b - q2a));
}

__global__ __launch_bounds__(1024) void trilin_lds_kernel(
    const float* __restrict__ img, const unsigned* __restrict__ lutq,
    const unsigned* __restrict__ maxbuf, float* __restrict__ out)
{
  constexpr int NPX = 720*1280;
  constexpr int NV4 = NPX/4;            // 230400
  constexpr int PER_BLK = NV4/32;       // 7200 float4-groups per block
  __shared__ unsigned s_lut[35937];     // 143,748 B

  const int tid = threadIdx.x;
  const int lin = blockIdx.x;           // bt + 8*bb, 256 blocks
  const int bt = lin & 7;
  const int bb = lin >> 3;              // 0..31
  const unsigned* Lg = lutq + (size_t)bt*35937;
  for (int i = tid; i < 35937; i += 1024) s_lut[i] = Lg[i];
  __syncthreads();

  const float maxv  = __uint_as_float(maxbuf[bt]);
  const float scale = maxv * (1.0f/511.0f);
  const float offc  = -512.0f * scale;
  const float* ib = img + (size_t)bt*3*NPX;
  float* ob = out + (size_t)bt*3*NPX;
  const float invbin = 32.0f/1.000001f;
  const int vend = bb*PER_BLK + PER_BLK;

  for (int v = bb*PER_BLK + tid; v < vend; v += 1024) {
    float4 r4 = ((const float4*)ib)[v];
    float4 g4 = ((const float4*)(ib + NPX))[v];
    float4 b4 = ((const float4*)(ib + 2*NPX))[v];
    float4 ro, go, bo;
    float* rp = (float*)&ro; float* gp = (float*)&go; float* bp = (float*)&bo;
    #pragma unroll
    for (int j = 0; j < 4; ++j) {
      float r = ((float*)&r4)[j], g = ((float*)&g4)[j], b = ((float*)&b4)[j];
      float pr = r*invbin, pg = g*invbin, pb = b*invbin;
      int ri = (int)pr; ri = ri > 31 ? 31 : ri; ri = ri < 0 ? 0 : ri;
      int gi = (int)pg; gi = gi > 31 ? 31 : gi; gi = gi < 0 ? 0 : gi;
      int bi = (int)pb; bi = bi > 31 ? 31 : bi; bi = bi < 0 ? 0 : bi;
      float fr = pr - ri, fg = pg - gi, fb = pb - bi;
      int i00 = (bi*33 + gi)*33 + ri;
      unsigned c00a = s_lut[i00],        c00b = s_lut[i00 + 1];
      unsigned c01a = s_lut[i00 + 33],   c01b = s_lut[i00 + 34];
      unsigned c10a = s_lut[i00 + 1089], c10b = s_lut[i00 + 1090];
      unsigned c11a = s_lut[i00 + 1122], c11b = s_lut[i00 + 1123];
      float wb0 = 1.f - fb, wb1 = fb, wg0 = 1.f - fg, wg1 = fg;
      float a0 = 0.f, a1 = 0.f, a2 = 0.f;
      pair_acc(c00a, c00b, wb0*wg0, fr, a0, a1, a2);
      pair_acc(c01a, c01b, wb0*wg1, fr, a0, a1, a2);
      pair_acc(c10a, c10b, wb1*wg0, fr, a0, a1, a2);
      pair_acc(c11a, c11b, wb1*wg1, fr, a0, a1, a2);
      rp[j] = a0*scale + offc + r;
      gp[j] = a1*scale + offc + g;
      bp[j] = a2*scale + offc + b;
    }
    ((float4*)ob)[v]           = ro;
    ((float4*)(ob + NPX))[v]   = go;
    ((float4*)(ob + 2*NPX))[v] = bo;
  }
}

// ---------------- launcher ----------------
extern "C" void kernel_launch(void* const* d_in, const int* in_sizes, int n_in,
                              void* d_out, int out_size, void* d_ws, size_t ws_size,
                              hipStream_t stream) {
  const float* img     = (const float*)d_in[0];
  const float* img_org = (const float*)d_in[1];
  const float* c0w = (const float*)d_in[2];  const float* c0b = (const float*)d_in[3];
  const float* c1w = (const float*)d_in[4];  const float* c1b = (const float*)d_in[5];
  const float* c2w = (const float*)d_in[6];  const float* c2b = (const float*)d_in[7];
  const float* c3w = (const float*)d_in[8];  const float* c3b = (const float*)d_in[9];
  const float* c4w = (const float*)d_in[10]; const float* c4b = (const float*)d_in[11];
  const float* n0g = (const float*)d_in[12]; const float* n0b = (const float*)d_in[13];
  const float* n1g = (const float*)d_in[14]; const float* n1b = (const float*)d_in[15];
  const float* n2g = (const float*)d_in[16]; const float* n2b = (const float*)d_in[17];
  const float* n3g = (const float*)d_in[18]; const float* n3b = (const float*)d_in[19];
  const float* cls0_w = (const float*)d_in[20]; const float* cls0_b = (const float*)d_in[21];
  const float* cls1_w = (const float*)d_in[22]; const float* cls1_b = (const float*)d_in[23];
  const float* s_layers = (const float*)d_in[24];
  const float* w_layers = (const float*)d_in[25];
  const float* luts     = (const float*)d_in[26];
  float* ws = (float*)d_ws;
  float* out = (float*)d_out;

  // zero stats + featsum + maxbuf
  zero_k<<<20, 256, 0, stream>>>(ws + OFF_STATB, 4872);

  // conv0: fp32 input, h2 output. TH=4 OCG=16 PX=8 OCT=2, BLK=512, grid 256
  conv_f32_first<3,16,256,256, 4,16, 8,2, 512><<<256, 512, 0, stream>>>(
      img, c0w, c0b, (h2*)(ws + OFF_Y0), ws + OFF_STAT0);
  // conv1-4: h2 in/out, dot2, LDS-staged weights, round-13 geometry
  conv_h2<16,32,128,128, 2,32, 4,2, 512, 1, 16384><<<256, 512, 0, stream>>>(
      (const h2*)(ws + OFF_Y0), c1w, c1b, ws + OFF_STAT0, n0g, n0b,
      (h2*)(ws + OFF_Y1), ws + OFF_STAT1);
  conv_h2<32,64,64,64, 2,32, 2,2, 512, 1, 4096><<<256, 512, 0, stream>>>(
      (const h2*)(ws + OFF_Y1), c2w, c2b, ws + OFF_STAT1, n1g, n1b,
      (h2*)(ws + OFF_Y2), ws + OFF_STAT2);
  conv_h2<64,128,32,32, 2,32, 1,2, 512, 1, 1024><<<256, 512, 0, stream>>>(
      (const h2*)(ws + OFF_Y2), c3w, c3b, ws + OFF_STAT2, n2g, n2b,
      (h2*)(ws + OFF_Y3), ws + OFF_STAT3);
  conv_h2<128,128,16,16, 2,16, 1,1, 256, 2, 256><<<256, 256, 0, stream>>>(
      (const h2*)(ws + OFF_Y3), c4w, c4b, ws + OFF_STAT3, n3g, n3b,
      nullptr, ws + OFF_FEATS);

  // U directly from luts/wl with in-block head
  u_direct_kernel<<<600, 256, 0, stream>>>(
      ws + OFF_FEATS, cls0_w, cls0_b, cls1_w, cls1_b,
      luts, w_layers, ws + OFF_U);

  // compact fp16 LUT + per-batch absmax
  lutc_max_kernel<<<141*8, 256, 0, stream>>>(
      ws + OFF_U, s_layers, (uint2*)(ws + OFF_LUTC), (unsigned*)(ws + OFF_MAXB));

  // quantize to 3x10-bit codes
  lutq_kernel<<<141*8, 256, 0, stream>>>(
      (const uint2*)(ws + OFF_LUTC), (const unsigned*)(ws + OFF_MAXB),
      (unsigned*)(ws + OFF_LUTQ));

  // trilinear from LDS-resident code table
  trilin_lds_kernel<<<256, 1024, 0, stream>>>(
      img_org, (const unsigned*)(ws + OFF_LUTQ), (const unsigned*)(ws + OFF_MAXB), out);
}

// Round 18
// 170.475 us; speedup vs baseline: 1.3962x; 1.0468x over previous
//
#include <hip/hip_runtime.h>
#include <hip/hip_fp16.h>

typedef _Float16 h2 __attribute__((ext_vector_type(2)));

// ---------------- workspace layout (float offsets) ----------------
constexpr size_t OFF_Y0    = 0;         // h2 activations (half-size)
constexpr size_t OFF_Y1    = 2097152;
constexpr size_t OFF_Y2    = 3145728;
constexpr size_t OFF_Y3    = 3670016;
constexpr size_t OFF_U     = 3670016 + 65536;  // 8*15*1089 = 130680
constexpr size_t OFF_LUTC  = 1048576;   // compact fp16: 8*35937 uint2
constexpr size_t OFF_LUTQ  = 2400000;   // 10-bit codes: 8*35937 dwords
constexpr size_t OFF_STATB = 4926640;
constexpr size_t OFF_STAT0 = OFF_STATB + 0;
constexpr size_t OFF_STAT1 = OFF_STATB + 256;
constexpr size_t OFF_STAT2 = OFF_STATB + 768;
constexpr size_t OFF_STAT3 = OFF_STATB + 1792;
constexpr size_t OFF_FEATS = OFF_STATB + 3840;
constexpr size_t OFF_MAXB  = OFF_STATB + 4864;

__global__ __launch_bounds__(256) void zero_k(float* __restrict__ p, int n) {
  int i = blockIdx.x*256 + threadIdx.x;
  if (i < n) p[i] = 0.f;
}

// ---------------- conv0: fp32 input (img), h2 pair output; weights LDS-staged ----------------
template<int CIN, int COUT, int HIN, int WIN, int TH, int OCG, int PX, int OCT, int BLK>
__global__ __launch_bounds__(BLK) void conv_f32_first(
    const float* __restrict__ xin, const float* __restrict__ wgt,
    const float* __restrict__ bias,
    h2* __restrict__ yout, float* __restrict__ stat_out)
{
  constexpr int HOUT = HIN/2, WOUT = WIN/2;
  constexpr int SEG  = WOUT + 4;
  constexpr int XROW = 2*SEG;
  constexpr int XPI  = (2*TH+1)*XROW;
  constexpr int NT   = HOUT/TH;
  constexpr int NSTRIP_B = TH*WOUT/PX;
  constexpr int GPT  = OCG/OCT;
  static_assert(BLK == NSTRIP_B*GPT, "thread mapping mismatch");
  static_assert(OCT == 2, "pair write");
  constexpr int R = NSTRIP_B < 64 ? NSTRIP_B : 64;

  __shared__ __align__(16) float xs[CIN*XPI];
  __shared__ float s_w[CIN*9*OCG];
  __shared__ float s_sc[CIN], s_sf[CIN];

  const int tid = threadIdx.x;
  const int lin = blockIdx.x;
  const int b = lin & 7;
  const int r2 = lin >> 3;
  const int tile = r2 % NT;
  const int ocb  = r2 / NT;

  if (tid == 0)      { s_sc[0] = 1.f/0.229f; s_sf[0] = -0.485f/0.229f; }
  else if (tid == 1) { s_sc[1] = 1.f/0.224f; s_sf[1] = -0.456f/0.224f; }
  else if (tid == 2) { s_sc[2] = 1.f/0.225f; s_sf[2] = -0.406f/0.225f; }
  __syncthreads();

  for (int e = tid; e < OCG*CIN*9; e += BLK) {
    int ocl = e / (CIN*9);
    int rem = e - ocl*(CIN*9);
    int ic = rem / 9, t = rem - ic*9;
    s_w[(ic*9 + t)*OCG + ocl] = wgt[((size_t)(ocb*OCG + ocl)*CIN + ic)*9 + t];
  }

  const int iy0 = tile*(2*TH) - 1;
  const float* xb_g = xin + (size_t)b*CIN*HIN*WIN;
  for (int e = tid; e < CIN*(2*TH+1)*(WIN+2); e += BLK) {
    int ic  = e / ((2*TH+1)*(WIN+2));
    int rem = e - ic*((2*TH+1)*(WIN+2));
    int rr  = rem / (WIN+2);
    int cc  = rem - rr*(WIN+2);
    int iy = iy0 + rr, ix = cc - 1;
    float v = 0.f;
    if (iy >= 0 && iy < HIN && ix >= 0 && ix < WIN)
      v = s_sc[ic]*xb_g[(size_t)ic*HIN*WIN + iy*WIN + ix] + s_sf[ic];
    int off = (ix & 1) ? (SEG + ((ix+1) >> 1)) : (ix >> 1);
    xs[ic*XPI + rr*XROW + off] = v;
  }
  __syncthreads();

  const int s  = tid % NSTRIP_B;
  const int g  = tid / NSTRIP_B;
  const int r  = s / (WOUT/PX);
  const int c0 = (s % (WOUT/PX)) * PX;
  const int oc0 = ocb*OCG + g*OCT;

  float acc[OCT][PX];
  #pragma unroll
  for (int k = 0; k < OCT; ++k) {
    float bb = bias[oc0+k];
    #pragma unroll
    for (int j = 0; j < PX; ++j) acc[k][j] = bb;
  }

  for (int ic = 0; ic < CIN; ++ic) {
    float wv[OCT][9];
    #pragma unroll
    for (int t = 0; t < 9; ++t) {
      #pragma unroll
      for (int k = 0; k < OCT; ++k)
        wv[k][t] = s_w[(ic*9 + t)*OCG + g*OCT + k];
    }
    const float* xb = xs + ic*XPI;
    #pragma unroll
    for (int ky = 0; ky < 3; ++ky) {
      const float* rowp = xb + (2*r+ky)*XROW;
      float eb[PX], ob[PX+1];
      static_assert(PX == 8, "conv0 uses PX=8");
      *(float4*)&eb[0] = *(const float4*)(rowp + c0);
      *(float4*)&eb[4] = *(const float4*)(rowp + c0 + 4);
      *(float4*)&ob[0] = *(const float4*)(rowp + SEG + c0);
      *(float4*)&ob[4] = *(const float4*)(rowp + SEG + c0 + 4);
      ob[8] = rowp[SEG + c0 + 8];
      #pragma unroll
      for (int k = 0; k < OCT; ++k) {
        float w0 = wv[k][ky*3], w1 = wv[k][ky*3+1], w2 = wv[k][ky*3+2];
        #pragma unroll
        for (int j = 0; j < PX; ++j)
          acc[k][j] += w0*ob[j] + w1*eb[j] + w2*ob[j+1];
      }
    }
  }

  const int oy = tile*TH + r;
  float ov[OCT][PX];
  float lsum[OCT], lsq[OCT];
  #pragma unroll
  for (int k = 0; k < OCT; ++k) {
    float ls = 0.f, lq = 0.f;
    #pragma unroll
    for (int j = 0; j < PX; ++j) {
      float a = acc[k][j];
      a = a >= 0.f ? a : 0.2f*a;
      ov[k][j] = a; ls += a; lq += a*a;
    }
    lsum[k] = ls; lsq[k] = lq;
  }
  h2 ph[PX];
  #pragma unroll
  for (int j = 0; j < PX; ++j) { ph[j][0] = (_Float16)ov[0][j]; ph[j][1] = (_Float16)ov[1][j]; }
  h2* yp = yout + (((size_t)b*(COUT/2) + (oc0 >> 1))*HOUT + oy)*WOUT + c0;
  *(uint4*)yp       = *(uint4*)&ph[0];
  *(uint4*)(yp + 4) = *(uint4*)&ph[4];

  #pragma unroll
  for (int k = 0; k < OCT; ++k) {
    #pragma unroll
    for (int off = R/2; off > 0; off >>= 1) {
      lsum[k] += __shfl_down(lsum[k], off);
      lsq[k]  += __shfl_down(lsq[k],  off);
    }
  }
  if ((tid & (R-1)) == 0) {
    #pragma unroll
    for (int k = 0; k < OCT; ++k) {
      atomicAdd(&stat_out[(b*COUT + oc0 + k)*2 + 0], lsum[k]);
      atomicAdd(&stat_out[(b*COUT + oc0 + k)*2 + 1], lsq[k]);
    }
  }
}

// ---------------- conv1-4: h2 in/out, v_dot2, weights LDS-staged as h2 pairs ----------------
template<int CIN, int COUT, int HIN, int WIN, int TH, int OCG, int PX, int OCT,
         int BLK, int MODE, int NPXPREV>
__global__ __launch_bounds__(BLK) void conv_h2(
    const h2* __restrict__ xin, const float* __restrict__ wgt,
    const float* __restrict__ bias, const float* __restrict__ stat_in,
    const float* __restrict__ gam, const float* __restrict__ bet,
    h2* __restrict__ yout, float* __restrict__ stat_out)
{
  constexpr int CINH = CIN/2;
  constexpr int HOUT = HIN/2, WOUT = WIN/2;
  constexpr int SEG  = WOUT + 4;
  constexpr int XROW = 2*SEG;
  constexpr int XPI  = (2*TH+1)*XROW;
  constexpr int NT   = HOUT/TH;
  constexpr int NSTRIP_B = TH*WOUT/PX;
  constexpr int GPT  = OCG/OCT;
  static_assert(BLK == NSTRIP_B*GPT, "thread mapping mismatch");
  static_assert(OCT == 2 || MODE == 2, "pair write needs OCT=2");
  constexpr int R = NSTRIP_B < 64 ? NSTRIP_B : 64;

  __shared__ __align__(16) h2 xs[CINH*XPI];
  __shared__ h2 s_w[CINH*9*OCG];
  __shared__ float s_sc[CIN], s_sf[CIN];

  const int tid = threadIdx.x;
  const int lin = blockIdx.x;
  const int b = lin & 7;
  const int r2 = lin >> 3;
  const int tile = r2 % NT;
  const int ocb  = r2 / NT;

  if (tid < CIN) {
    float S = stat_in[(b*CIN+tid)*2+0], Q = stat_in[(b*CIN+tid)*2+1];
    float mean = S*(1.0f/NPXPREV);
    float var  = Q*(1.0f/NPXPREV) - mean*mean;
    float rstd = rsqrtf(var + 1e-5f);
    float gg = gam[tid], bb = bet[tid];
    s_sc[tid] = gg*rstd;
    s_sf[tid] = bb - mean*gg*rstd;
  }
  __syncthreads();

  for (int e = tid; e < OCG*CINH*9; e += BLK) {
    int ocl = e / (CINH*9);
    int rem = e - ocl*(CINH*9);
    int icp = rem / 9, t = rem - icp*9;
    const float* wp = wgt + ((size_t)(ocb*OCG + ocl)*CIN + 2*icp)*9 + t;
    h2 w; w[0] = (_Float16)wp[0]; w[1] = (_Float16)wp[9];
    s_w[(icp*9 + t)*OCG + ocl] = w;
  }

  const int iy0 = tile*(2*TH) - 1;
  const h2* xb_g = xin + (size_t)b*CINH*HIN*WIN;
  for (int e = tid; e < CINH*(2*TH+1)*(WIN+2); e += BLK) {
    int icp = e / ((2*TH+1)*(WIN+2));
    int rem = e - icp*((2*TH+1)*(WIN+2));
    int rr  = rem / (WIN+2);
    int cc  = rem - rr*(WIN+2);
    int iy = iy0 + rr, ix = cc - 1;
    float v0 = 0.f, v1 = 0.f;
    if (iy >= 0 && iy < HIN && ix >= 0 && ix < WIN) {
      h2 x = xb_g[(size_t)icp*HIN*WIN + iy*WIN + ix];
      int ic0 = 2*icp;
      v0 = s_sc[ic0]  *(float)x[0] + s_sf[ic0];
      v1 = s_sc[ic0+1]*(float)x[1] + s_sf[ic0+1];
    }
    int off = (ix & 1) ? (SEG + ((ix+1) >> 1)) : (ix >> 1);
    h2 p; p[0] = (_Float16)v0; p[1] = (_Float16)v1;
    xs[icp*XPI + rr*XROW + off] = p;
  }
  __syncthreads();

  const int s  = tid % NSTRIP_B;
  const int g  = tid / NSTRIP_B;
  const int r  = s / (WOUT/PX);
  const int c0 = (s % (WOUT/PX)) * PX;
  const int oc0 = ocb*OCG + g*OCT;

  float acc[OCT][PX];
  #pragma unroll
  for (int k = 0; k < OCT; ++k) {
    float bb = bias[oc0+k];
    #pragma unroll
    for (int j = 0; j < PX; ++j) acc[k][j] = bb;
  }

  for (int icp = 0; icp < CINH; ++icp) {
    h2 wv[OCT][9];
    #pragma unroll
    for (int t = 0; t < 9; ++t) {
      #pragma unroll
      for (int k = 0; k < OCT; ++k)
        wv[k][t] = s_w[(icp*9 + t)*OCG + g*OCT + k];
    }
    const h2* xb = xs + icp*XPI;
    #pragma unroll
    for (int ky = 0; ky < 3; ++ky) {
      const h2* rowp = xb + (2*r+ky)*XROW;
      h2 eb[PX], ob[PX+1];
      if constexpr (PX == 4) {
        *(uint4*)&eb[0] = *(const uint4*)(rowp + c0);
        *(uint4*)&ob[0] = *(const uint4*)(rowp + SEG + c0);
        ob[4] = rowp[SEG + c0 + 4];
      } else if constexpr (PX == 2) {
        *(uint2*)&eb[0] = *(const uint2*)(rowp + c0);
        *(uint2*)&ob[0] = *(const uint2*)(rowp + SEG + c0);
        ob[2] = rowp[SEG + c0 + 2];
      } else {
        eb[0] = rowp[c0];
        ob[0] = rowp[SEG + c0];
        ob[1] = rowp[SEG + c0 + 1];
      }
      #pragma unroll
      for (int k = 0; k < OCT; ++k) {
        h2 w0 = wv[k][ky*3], w1 = wv[k][ky*3+1], w2 = wv[k][ky*3+2];
        #pragma unroll
        for (int j = 0; j < PX; ++j) {
          float a = acc[k][j];
          a = __builtin_amdgcn_fdot2(w0, ob[j],   a, false);
          a = __builtin_amdgcn_fdot2(w1, eb[j],   a, false);
          a = __builtin_amdgcn_fdot2(w2, ob[j+1], a, false);
          acc[k][j] = a;
        }
      }
    }
  }

  const int oy = tile*TH + r;
  if constexpr (MODE != 2) {
    float ov[OCT][PX];
    float lsum[OCT], lsq[OCT];
    #pragma unroll
    for (int k = 0; k < OCT; ++k) {
      float ls = 0.f, lq = 0.f;
      #pragma unroll
      for (int j = 0; j < PX; ++j) {
        float a = acc[k][j];
        a = a >= 0.f ? a : 0.2f*a;
        ov[k][j] = a; ls += a; lq += a*a;
      }
      lsum[k] = ls; lsq[k] = lq;
    }
    h2 ph[PX];
    #pragma unroll
    for (int j = 0; j < PX; ++j) { ph[j][0] = (_Float16)ov[0][j]; ph[j][1] = (_Float16)ov[1][j]; }
    h2* yp = yout + (((size_t)b*(COUT/2) + (oc0 >> 1))*HOUT + oy)*WOUT + c0;
    if constexpr (PX == 4) {
      *(uint4*)yp = *(uint4*)&ph[0];
    } else if constexpr (PX == 2) {
      *(uint2*)yp = *(uint2*)&ph[0];
    } else {
      yp[0] = ph[0];
    }
    #pragma unroll
    for (int k = 0; k < OCT; ++k) {
      #pragma unroll
      for (int off = R/2; off > 0; off >>= 1) {
        lsum[k] += __shfl_down(lsum[k], off);
        lsq[k]  += __shfl_down(lsq[k],  off);
      }
    }
    if ((tid & (R-1)) == 0) {
      #pragma unroll
      for (int k = 0; k < OCT; ++k) {
        atomicAdd(&stat_out[(b*COUT + oc0 + k)*2 + 0], lsum[k]);
        atomicAdd(&stat_out[(b*COUT + oc0 + k)*2 + 1], lsq[k]);
      }
    }
  } else {
    float a = acc[0][0];
    a = a >= 0.f ? a : 0.2f*a;
    #pragma unroll
    for (int off = R/2; off > 0; off >>= 1) a += __shfl_down(a, off);
    if ((tid & (R-1)) == 0) atomicAdd(&stat_out[b*COUT + oc0], a);
  }
}

// ---------------- U direct: head (redundant per block) + V fold + U slice ----------------
__global__ __launch_bounds__(256) void u_direct_kernel(
    const float* __restrict__ featsum, const float* __restrict__ w0, const float* __restrict__ b0,
    const float* __restrict__ w1, const float* __restrict__ b1,
    const float* __restrict__ luts, const float* __restrict__ wl, float* __restrict__ U)
{
  __shared__ float sh_h[128];
  __shared__ float sh_w[20];
  __shared__ float sh_v[20];
  const int tid = threadIdx.x;
  const int lin = blockIdx.x;            // bt + 8*(j*5+qb), 600 blocks
  const int bt = lin & 7;
  const int rest = lin >> 3;             // 0..74
  const int j = rest / 5, qb = rest % 5;
  const int s = j / 3, ch = j % 3;

  if (tid < 128) {
    const float* f = featsum + bt*128;
    const float* w = w0 + tid*128;
    float a = 0.f;
    for (int k = 0; k < 128; ++k) a += f[k]*w[k];
    a = b0[tid] + a*(1.0f/64.0f);
    float c = fminf(fmaxf(a + 3.f, 0.f), 6.f);
    sh_h[tid] = a * c * (1.f/6.f);
  }
  __syncthreads();
  if (tid < 20) {
    const float* w = w1 + tid*128;
    float a = b1[tid];
    for (int k = 0; k < 128; ++k) a += sh_h[k]*w[k];
    sh_w[tid] = a;
  }
  __syncthreads();
  if (tid < 20) {
    float a = 0.f;
    #pragma unroll
    for (int n = 0; n < 20; ++n)
      a += sh_w[n] * luts[(s*60 + n*3 + ch)*20 + tid];
    sh_v[tid] = a;
  }
  __syncthreads();
  const int q = qb*256 + tid;
  if (q < 1089) {
    float a = 0.f;
    #pragma unroll
    for (int w = 0; w < 20; ++w) a += sh_v[w] * wl[w*1089 + q];
    U[(size_t)(bt*15 + j)*1089 + q] = a;
  }
}

// ---------------- compact fp16 LUT + per-batch absmax ----------------
__global__ __launch_bounds__(256) void lutc_max_kernel(
    const float* __restrict__ U, const float* __restrict__ slay,
    uint2* __restrict__ lutc, unsigned* __restrict__ maxbuf)
{
  __shared__ float s_slay[165];
  __shared__ unsigned s_max;
  const int tid = threadIdx.x;
  if (tid < 165) s_slay[tid] = slay[tid];
  if (tid == 0) s_max = 0u;
  __syncthreads();
  const int lin = blockIdx.x;            // bt + 8*chunk, 141*8 blocks
  const int bt = lin & 7;
  const int i = (lin >> 3)*256 + tid;
  if (i < 35937) {
    int bi = i / 1089, rem = i - bi*1089, gi = rem / 33, ri = rem - gi*33;
    const float* Ub = U + (size_t)bt*15*1089;
    float v0 = 0.f, v1 = 0.f, v2 = 0.f;
    #pragma unroll
    for (int s = 0; s < 5; ++s) {
      v0 += s_slay[ri*5+s] * Ub[(s*3+0)*1089 + bi*33 + gi];
      v1 += s_slay[gi*5+s] * Ub[(s*3+1)*1089 + bi*33 + ri];
      v2 += s_slay[bi*5+s] * Ub[(s*3+2)*1089 + gi*33 + ri];
    }
    union { __half2 h2v; unsigned u; } p0, p1;
    p0.h2v = __floats2half2_rn(v0, v1);
    p1.h2v = __floats2half2_rn(v2, 0.f);
    lutc[(size_t)bt*35937 + i] = make_uint2(p0.u, p1.u);
    float m = fmaxf(fmaxf(fabsf(v0), fabsf(v1)), fabsf(v2));
    atomicMax(&s_max, __float_as_uint(m));
  }
  __syncthreads();
  if (tid == 0) atomicMax(&maxbuf[bt], s_max);
}

// ---------------- quantize compact fp16 -> 3x10-bit codes (4B/corner) ----------------
__global__ __launch_bounds__(256) void lutq_kernel(
    const uint2* __restrict__ lutc, const unsigned* __restrict__ maxbuf,
    unsigned* __restrict__ lutq)
{
  const int lin = blockIdx.x;            // bt + 8*chunk, 141*8 blocks
  const int bt = lin & 7;
  const int i = (lin >> 3)*256 + threadIdx.x;
  if (i >= 35937) return;
  float maxv = __uint_as_float(maxbuf[bt]);
  float enc = maxv > 0.f ? 511.0f/maxv : 0.f;
  uint2 c = lutc[(size_t)bt*35937 + i];
  __half2 h01 = *(__half2*)&c.x;
  __half2 h2_ = *(__half2*)&c.y;
  float v0 = __low2float(h01), v1 = __high2float(h01), v2 = __low2float(h2_);
  int q0 = (int)rintf(v0*enc) + 512;
  int q1 = (int)rintf(v1*enc) + 512;
  int q2 = (int)rintf(v2*enc) + 512;
  q0 = q0 < 0 ? 0 : (q0 > 1023 ? 1023 : q0);
  q1 = q1 < 0 ? 0 : (q1 > 1023 ? 1023 : q1);
  q2 = q2 < 0 ? 0 : (q2 > 1023 ? 1023 : q2);
  lutq[(size_t)bt*35937 + i] = (unsigned)q0 | ((unsigned)q1 << 10) | ((unsigned)q2 << 20);
}

// ---------------- trilinear from LDS-resident quantized LUT + residual (pipelined) ---------
__device__ __forceinline__ void pair_acc(unsigned ca, unsigned cb, float wp, float fr,
                                         float& a0, float& a1, float& a2)
{
  float q0a = (float)(ca & 1023u), q1a = (float)((ca >> 10) & 1023u), q2a = (float)((ca >> 20) & 1023u);
  float q0b = (float)(cb & 1023u), q1b = (float)((cb >> 10) & 1023u), q2b = (float)((cb >> 20) & 1023u);
  a0 += wp * (q0a + fr*(q0b - q0a));
  a1 += wp * (q1a + fr*(q1b - q1a));
  a2 += wp * (q2a + fr*(q2b - q2a));
}

__global__ __launch_bounds__(1024) void trilin_lds_kernel(
    const float* __restrict__ img, const unsigned* __restrict__ lutq,
    const unsigned* __restrict__ maxbuf, float* __restrict__ out)
{
  constexpr int NPX = 720*1280;
  constexpr int NV4 = NPX/4;            // 230400
  constexpr int PER_BLK = NV4/32;       // 7200 float4-groups per block
  __shared__ unsigned s_lut[35937];     // 143,748 B

  const int tid = threadIdx.x;
  const int lin = blockIdx.x;           // bt + 8*bb, 256 blocks
  const int bt = lin & 7;
  const int bb = lin >> 3;              // 0..31
  const unsigned* Lg = lutq + (size_t)bt*35937;
  for (int i = tid; i < 35937; i += 1024) s_lut[i] = Lg[i];
  __syncthreads();

  const float maxv  = __uint_as_float(maxbuf[bt]);
  const float scale = maxv * (1.0f/511.0f);
  const float offc  = -512.0f * scale;
  const float* ib = img + (size_t)bt*3*NPX;
  float* ob = out + (size_t)bt*3*NPX;
  const float invbin = 32.0f/1.000001f;
  const int vend = bb*PER_BLK + PER_BLK;

  // software-pipelined loop: issue next iteration's img loads before computing current
  int v = bb*PER_BLK + tid;
  bool valid = v < vend;
  float4 r4, g4, b4;
  if (valid) {
    r4 = ((const float4*)ib)[v];
    g4 = ((const float4*)(ib + NPX))[v];
    b4 = ((const float4*)(ib + 2*NPX))[v];
  }
  while (valid) {
    const int vn = v + 1024;
    const bool nvalid = vn < vend;
    float4 rn, gn, bn;
    if (nvalid) {
      rn = ((const float4*)ib)[vn];
      gn = ((const float4*)(ib + NPX))[vn];
      bn = ((const float4*)(ib + 2*NPX))[vn];
    }
    float4 ro, go, bo;
    float* rp = (float*)&ro; float* gp = (float*)&go; float* bp = (float*)&bo;
    #pragma unroll
    for (int j = 0; j < 4; ++j) {
      float r = ((float*)&r4)[j], g = ((float*)&g4)[j], b = ((float*)&b4)[j];
      float pr = r*invbin, pg = g*invbin, pb = b*invbin;
      int ri = (int)pr; ri = ri > 31 ? 31 : ri; ri = ri < 0 ? 0 : ri;
      int gi = (int)pg; gi = gi > 31 ? 31 : gi; gi = gi < 0 ? 0 : gi;
      int bi = (int)pb; bi = bi > 31 ? 31 : bi; bi = bi < 0 ? 0 : bi;
      float fr = pr - ri, fg = pg - gi, fb = pb - bi;
      int i00 = (bi*33 + gi)*33 + ri;
      unsigned c00a = s_lut[i00],        c00b = s_lut[i00 + 1];
      unsigned c01a = s_lut[i00 + 33],   c01b = s_lut[i00 + 34];
      unsigned c10a = s_lut[i00 + 1089], c10b = s_lut[i00 + 1090];
      unsigned c11a = s_lut[i00 + 1122], c11b = s_lut[i00 + 1123];
      float wb0 = 1.f - fb, wb1 = fb, wg0 = 1.f - fg, wg1 = fg;
      float a0 = 0.f, a1 = 0.f, a2 = 0.f;
      pair_acc(c00a, c00b, wb0*wg0, fr, a0, a1, a2);
      pair_acc(c01a, c01b, wb0*wg1, fr, a0, a1, a2);
      pair_acc(c10a, c10b, wb1*wg0, fr, a0, a1, a2);
      pair_acc(c11a, c11b, wb1*wg1, fr, a0, a1, a2);
      rp[j] = a0*scale + offc + r;
      gp[j] = a1*scale + offc + g;
      bp[j] = a2*scale + offc + b;
    }
    ((float4*)ob)[v]           = ro;
    ((float4*)(ob + NPX))[v]   = go;
    ((float4*)(ob + 2*NPX))[v] = bo;
    v = vn; valid = nvalid;
    r4 = rn; g4 = gn; b4 = bn;
  }
}

// ---------------- launcher ----------------
extern "C" void kernel_launch(void* const* d_in, const int* in_sizes, int n_in,
                              void* d_out, int out_size, void* d_ws, size_t ws_size,
                              hipStream_t stream) {
  const float* img     = (const float*)d_in[0];
  const float* img_org = (const float*)d_in[1];
  const float* c0w = (const float*)d_in[2];  const float* c0b = (const float*)d_in[3];
  const float* c1w = (const float*)d_in[4];  const float* c1b = (const float*)d_in[5];
  const float* c2w = (const float*)d_in[6];  const float* c2b = (const float*)d_in[7];
  const float* c3w = (const float*)d_in[8];  const float* c3b = (const float*)d_in[9];
  const float* c4w = (const float*)d_in[10]; const float* c4b = (const float*)d_in[11];
  const float* n0g = (const float*)d_in[12]; const float* n0b = (const float*)d_in[13];
  const float* n1g = (const float*)d_in[14]; const float* n1b = (const float*)d_in[15];
  const float* n2g = (const float*)d_in[16]; const float* n2b = (const float*)d_in[17];
  const float* n3g = (const float*)d_in[18]; const float* n3b = (const float*)d_in[19];
  const float* cls0_w = (const float*)d_in[20]; const float* cls0_b = (const float*)d_in[21];
  const float* cls1_w = (const float*)d_in[22]; const float* cls1_b = (const float*)d_in[23];
  const float* s_layers = (const float*)d_in[24];
  const float* w_layers = (const float*)d_in[25];
  const float* luts     = (const float*)d_in[26];
  float* ws = (float*)d_ws;
  float* out = (float*)d_out;

  // zero stats + featsum + maxbuf
  zero_k<<<20, 256, 0, stream>>>(ws + OFF_STATB, 4872);

  // conv0: fp32 input, h2 output
  conv_f32_first<3,16,256,256, 4,16, 8,2, 512><<<256, 512, 0, stream>>>(
      img, c0w, c0b, (h2*)(ws + OFF_Y0), ws + OFF_STAT0);
  // conv1-4: h2 in/out, dot2, LDS-staged weights
  conv_h2<16,32,128,128, 2,32, 4,2, 512, 1, 16384><<<256, 512, 0, stream>>>(
      (const h2*)(ws + OFF_Y0), c1w, c1b, ws + OFF_STAT0, n0g, n0b,
      (h2*)(ws + OFF_Y1), ws + OFF_STAT1);
  conv_h2<32,64,64,64, 2,32, 2,2, 512, 1, 4096><<<256, 512, 0, stream>>>(
      (const h2*)(ws + OFF_Y1), c2w, c2b, ws + OFF_STAT1, n1g, n1b,
      (h2*)(ws + OFF_Y2), ws + OFF_STAT2);
  conv_h2<64,128,32,32, 2,32, 1,2, 512, 1, 1024><<<256, 512, 0, stream>>>(
      (const h2*)(ws + OFF_Y2), c3w, c3b, ws + OFF_STAT2, n2g, n2b,
      (h2*)(ws + OFF_Y3), ws + OFF_STAT3);
  conv_h2<128,128,16,16, 2,16, 1,1, 256, 2, 256><<<256, 256, 0, stream>>>(
      (const h2*)(ws + OFF_Y3), c4w, c4b, ws + OFF_STAT3, n3g, n3b,
      nullptr, ws + OFF_FEATS);

  // U directly from luts/wl with in-block head
  u_direct_kernel<<<600, 256, 0, stream>>>(
      ws + OFF_FEATS, cls0_w, cls0_b, cls1_w, cls1_b,
      luts, w_layers, ws + OFF_U);

  // compact fp16 LUT + per-batch absmax
  lutc_max_kernel<<<141*8, 256, 0, stream>>>(
      ws + OFF_U, s_layers, (uint2*)(ws + OFF_LUTC), (unsigned*)(ws + OFF_MAXB));

  // quantize to 3x10-bit codes
  lutq_kernel<<<141*8, 256, 0, stream>>>(
      (const uint2*)(ws + OFF_LUTC), (const unsigned*)(ws + OFF_MAXB),
      (unsigned*)(ws + OFF_LUTQ));

  // trilinear from LDS-resident code table (software-pipelined img loads)
  trilin_lds_kernel<<<256, 1024, 0, stream>>>(
      img_org, (const unsigned*)(ws + OFF_LUTQ), (const unsigned*)(ws + OFF_MAXB), out);
}